// Round 10
// baseline (261.129 us; speedup 1.0000x reference)
//
#include <hip/hip_runtime.h>
#include <stdint.h>

#define NB 8
#define NC 256
#define NHW 4096
#define NG 32
#define GELEMS (8*NHW)
#define EPS 1e-5f

typedef unsigned short u16;
typedef unsigned int u32;
typedef __attribute__((ext_vector_type(8))) short bf16x8;
typedef __attribute__((ext_vector_type(4))) float f32x4;
typedef __attribute__((ext_vector_type(16))) float f32x16;

__device__ __forceinline__ float bf2f(u16 u){ return __uint_as_float((u32)u << 16); }
__device__ __forceinline__ u16 f2bf(float f){
  u32 i = __float_as_uint(f);
  u32 r = i + 0x7fffu + ((i >> 16) & 1u);   // RNE
  return (u16)(r >> 16);
}
__device__ __forceinline__ u32 pack2(float a, float b){
  return (u32)f2bf(a) | ((u32)f2bf(b) << 16);
}
__device__ __forceinline__ u32 cvtpk(float lo, float hi){
  u32 r;
  asm("v_cvt_pk_bf16_f32 %0, %1, %2" : "=v"(r) : "v"(lo), "v"(hi));
  return r;
}
__device__ __forceinline__ void plswap(u32 &a, u32 &b){
  asm volatile("v_permlane32_swap_b32 %0, %1" : "+v"(a), "+v"(b));
}

#define GLD16(g, l) __builtin_amdgcn_global_load_lds( \
    (const __attribute__((address_space(1))) u32*)(g), \
    (__attribute__((address_space(3))) u32*)(l), 16, 0, 0)

// ---------------- GroupNorm statistics ----------------
__global__ __launch_bounds__(256) void gn_stats_k(const float* __restrict__ x,
                                                  float* __restrict__ stats){
  int bg = blockIdx.x;
  const float* xp = x + (size_t)bg * GELEMS;
  float s = 0.f, s2 = 0.f;
  for (int i = threadIdx.x * 4; i < GELEMS; i += 256 * 4) {
    float4 v = *(const float4*)(xp + i);
    s  += v.x + v.y + v.z + v.w;
    s2 += v.x*v.x + v.y*v.y + v.z*v.z + v.w*v.w;
  }
  #pragma unroll
  for (int off = 32; off; off >>= 1) { s += __shfl_xor(s, off); s2 += __shfl_xor(s2, off); }
  __shared__ float rs[4], rs2[4];
  int w = threadIdx.x >> 6;
  if ((threadIdx.x & 63) == 0) { rs[w] = s; rs2[w] = s2; }
  __syncthreads();
  if (threadIdx.x == 0) {
    float ts = rs[0]+rs[1]+rs[2]+rs[3], t2 = rs2[0]+rs2[1]+rs2[2]+rs2[3];
    float mean = ts * (1.f/GELEMS);
    float var  = t2 * (1.f/GELEMS) - mean*mean;
    stats[2*bg]   = mean;
    stats[2*bg+1] = rsqrtf(var + EPS);
  }
}

__global__ __launch_bounds__(256) void gn_coef_k(const float* __restrict__ stats,
                                                 const float* __restrict__ gamma,
                                                 const float* __restrict__ beta,
                                                 float* __restrict__ coef){
  int i = blockIdx.x * 256 + threadIdx.x;
  if (i >= NB*NC) return;
  int b = i >> 8, c = i & 255;
  float mean = stats[2*(b*NG + (c>>3))];
  float rstd = stats[2*(b*NG + (c>>3)) + 1];
  float sc = gamma[c] * rstd;
  coef[2*i]   = sc;
  coef[2*i+1] = beta[c] - mean * sc;
}

__global__ __launch_bounds__(256) void cvtw_k(const float* __restrict__ w,
                                              u16* __restrict__ wbf){
  int i = blockIdx.x * 256 + threadIdx.x;
  wbf[i] = f2bf(w[i]);
}

// fragment-linear proj W for 32x32 MFMA B-operand: chunk (ot*16+ks)*64+l holds
// W^T[c = ks*16+(l>>5)*8 + e][o = ot*32+(l&31)]
__global__ __launch_bounds__(256) void cvtw2_k(const float* __restrict__ w,
                                               u16* __restrict__ wf){
  int i = blockIdx.x * 256 + threadIdx.x;     // 65536
  int e = i & 7, chunk = i >> 3;
  int l = chunk & 63, ks = (chunk >> 6) & 15, ot = chunk >> 10;
  int c = ks*16 + (l>>5)*8 + e;
  int o = ot*32 + (l&31);
  wf[i] = f2bf(w[o*NC + c]);
}

// -------- MFMA fused GN + QKV --------
// Q -> [n][c] bf16 (pre-scaled 1/16).
// K -> fragment-linear: elem(m,c) at ((t*16+kcc)*64 + l)*8 + e,
//      t=m>>5, kcc=c>>4, l=(m&31)+32*((c>>3)&1), e=c&7.
// V -> fragment-linear: elem(c,m) at ((t*16+cv)*64 + l)*8 + e,
//      t=m>>5, cv=((c>>5)&7)+8*((m&31)>>4), l=(c&31)+32*((m>>3)&1), e=m&7.
__global__ __launch_bounds__(256, 2) void qkv_mfma_k(const float* __restrict__ x,
    const float* __restrict__ coef, const u16* __restrict__ wqbf,
    const float* __restrict__ b_qkv,
    u16* __restrict__ qT, u16* __restrict__ kF, u16* __restrict__ vF){
  __shared__ u16 Wbuf[2][4096];              // [16][256] bf16, chunk^=(row&7)

  int bid = blockIdx.x;
  int wg = ((bid & 7) << 6) | (bid >> 3);    // XCD swizzle: batch b -> XCD b
  int b  = wg >> 6;
  int n0 = (wg & 63) << 6;
  int w = threadIdx.x >> 6, lane = threadIdx.x & 63;
  int lo = lane & 15, g = lane >> 4;
  int n = n0 + w*16 + lo;

  int row1 = w*2 + (lane >> 5);
  int sxor = ((lane & 31) ^ (row1 & 7)) * 8;
  int src1 = row1 * 256 + sxor;
  int src2 = (row1 + 8) * 256 + sxor;

  auto STAGE = [&](int bufi, int ot) {
    const u16* src = wqbf + ot * 4096;
    GLD16(src + src1, &Wbuf[bufi][w * 512]);
    GLD16(src + src2, &Wbuf[bufi][2048 + w * 512]);
  };

  STAGE(0, 0);

  bf16x8 hf[8];
  {
    const float* xb = x + (size_t)b * NC * NHW + n;
    const float* cf = coef + b * 512;
    #pragma unroll
    for (int kc = 0; kc < 8; ++kc) {
      union { u32 u[4]; bf16x8 v; } hu;
      #pragma unroll
      for (int p = 0; p < 4; ++p) {
        int c = kc*32 + g*8 + p*2;
        float2 s0 = *(const float2*)(cf + 2*c);
        float2 s1 = *(const float2*)(cf + 2*c + 2);
        float f0 = xb[(size_t)c * NHW]     * s0.x + s0.y;
        float f1 = xb[(size_t)(c+1) * NHW] * s1.x + s1.y;
        hu.u[p] = pack2(f0, f1);
      }
      hf[kc] = hu.v;
    }
  }

  u16* qrow = qT + ((size_t)(b * NHW + n)) * NC;
  u16* kFb = kF + (size_t)b * NHW * NC;
  u16* vFb = vF + (size_t)b * NHW * NC;

  for (int ot = 0; ot < 48; ++ot) {
    __syncthreads();
    if (ot < 47) STAGE((ot + 1) & 1, ot + 1);
    const u16* Wl = Wbuf[ot & 1];
    int sw = lo & 7;
    f32x4 acc = (f32x4){0.f, 0.f, 0.f, 0.f};

    if (ot < 32) {
      // C[o][j]: o = ot*16+4g+r, j (pixel) = lo
      #pragma unroll
      for (int kc = 0; kc < 8; ++kc) {
        bf16x8 wf = *(const bf16x8*)(Wl + lo*256 + ((kc*4 + g) ^ sw) * 8);
        acc = __builtin_amdgcn_mfma_f32_16x16x32_bf16(wf, hf[kc], acc, 0, 0, 0);
      }
      float4 bq = *(const float4*)(b_qkv + ot*16 + 4*g);
      float v0 = acc[0]+bq.x, v1 = acc[1]+bq.y, v2 = acc[2]+bq.z, v3 = acc[3]+bq.w;
      if (ot < 16) {                          // Q, scaled
        v0 *= 0.0625f; v1 *= 0.0625f; v2 *= 0.0625f; v3 *= 0.0625f;
        uint2 st = { pack2(v0, v1), pack2(v2, v3) };
        *(uint2*)(qrow + ot*16 + 4*g) = st;
      } else {                                // K fragment-linear: c = (ot-16)*16+4g+r, m = n
        uint2 st = { pack2(v0, v1), pack2(v2, v3) };
        int cb = (ot-16)*16 + 4*g;
        int l = (n & 31) + 32*((cb >> 3) & 1);
        size_t addr = (((size_t)(n >> 5)*16 + (ot-16))*64 + l)*8 + (cb & 7);
        *(uint2*)(kFb + addr) = st;
      }
    } else {
      // swapped: C[j][o]: j (pixel m) = 4g+r local, o (channel c) = (ot-32)*16+lo
      #pragma unroll
      for (int kc = 0; kc < 8; ++kc) {
        bf16x8 wf = *(const bf16x8*)(Wl + lo*256 + ((kc*4 + g) ^ sw) * 8);
        acc = __builtin_amdgcn_mfma_f32_16x16x32_bf16(hf[kc], wf, acc, 0, 0, 0);
      }
      int oc = (ot - 32) * 16 + lo;           // channel c
      float bv = b_qkv[512 + oc];
      uint2 st = { pack2(acc[0]+bv, acc[1]+bv), pack2(acc[2]+bv, acc[3]+bv) };
      int m = n0 + w*16 + 4*g;                // pixel base (4 consecutive m in elems)
      int cv = ((oc >> 5) & 7) + 8*(w & 1);
      int l = (oc & 31) + 32*((w*2 + (g >> 1)) & 1);
      size_t addr = (((size_t)(m >> 5)*16 + cv)*64 + l)*8 + ((4*g) & 7);
      *(uint2*)(vFb + addr) = st;
    }
  }
}

// ---------------- scalar qkv fallback (old layouts) ----------------
__global__ __launch_bounds__(256) void qkv_scalar_k(const float* __restrict__ x,
                                             const float* __restrict__ coef,
                                             const float* __restrict__ w_qkv,
                                             const float* __restrict__ b_qkv,
                                             u16* __restrict__ qT, u16* __restrict__ kT,
                                             u16* __restrict__ vS){
  int idx0 = blockIdx.x;
  int idx = (idx0 >> 3) + (idx0 & 7) * 768;
  int og = idx % 48;
  int t  = idx / 48;
  int nc = t & 15;
  int b  = t >> 4;
  int n  = nc * 256 + threadIdx.x;
  const float* xb = x + (size_t)b * NC * NHW + n;
  const float* cf = coef + b * NC * 2;
  int ob = og * 16;
  float acc[16];
  #pragma unroll
  for (int j = 0; j < 16; ++j) acc[j] = b_qkv[ob + j];
  for (int c = 0; c < NC; ++c) {
    float h = xb[(size_t)c * NHW] * cf[2*c] + cf[2*c+1];
    const float* wr = w_qkv + (size_t)ob * NC + c;
    #pragma unroll
    for (int j = 0; j < 16; ++j) acc[j] += h * wr[(size_t)j * NC];
  }
  if (ob < 512) {
    float sc = (ob < 256) ? 0.0625f : 1.0f;
    union { u16 h[16]; uint4 q[2]; } u;
    #pragma unroll
    for (int j = 0; j < 16; ++j) u.h[j] = f2bf(acc[j] * sc);
    u16* p = (ob < 256) ? (qT + ((size_t)(b*NHW + n))*NC + ob)
                        : (kT + ((size_t)(b*NHW + n))*NC + (ob - 256));
    *(uint4*)p = u.q[0];
    *(uint4*)(p + 8) = u.q[1];
  } else {
    u16* p = vS + ((size_t)(b*NC) + (ob - 512)) * NHW + n;
    #pragma unroll
    for (int j = 0; j < 16; ++j) p[(size_t)j * NHW] = f2bf(acc[j]);
  }
}

// ========== split-KV flash attention, 32x32 MFMA, fragment-linear K/V (R8 cfg) ==========
// 512 blocks = (b=8) x (rowblk=32) x (half=2); 4 waves x 32 rows; 2 blocks/CU.
// Staging = pure linear 16KB copy (coalesced); LDS reads contiguous 1KB (0 conflicts).
// No-max softmax; P in-register (cvt_pk + permlane32_swap); bf16 Praw; setprio on MFMA.
__global__ __launch_bounds__(256, 2) void attn_split_k(
    const u16* __restrict__ qT, const u16* __restrict__ kF, const u16* __restrict__ vF,
    const u16* __restrict__ wprojF, u16* __restrict__ Praw, float* __restrict__ lsum){
  __shared__ char smem[65536];
  // Kbuf[2] 16KB at 0; Vbuf[2] 16KB at 32768. Epilogue alias: per-wave O 16KB at w*16384.

  int bid = blockIdx.x;
  int b = bid & 7;                           // batch -> XCD
  int u = bid >> 3;
  int rb = u >> 1, h2 = u & 1;
  int n0 = rb << 7;
  int w = threadIdx.x >> 6, lane = threadIdx.x & 63;
  int ln = lane & 31, hl = lane >> 5;

  const u16* qTb = qT + (size_t)b * NHW * NC;
  const u16* kFb = kF + (size_t)b * NHW * NC;
  const u16* vFb = vF + (size_t)b * NHW * NC;

  int nrow = n0 + w*32 + ln;
  bf16x8 qf[16];
  {
    const u16* qp = qTb + (size_t)nrow * NC + hl*8;
    #pragma unroll
    for (int kc = 0; kc < 16; ++kc) qf[kc] = *(const bf16x8*)(qp + kc*16);
  }

  auto STAGE = [&](int bi, int tile){
    const u16* kp = kFb + (size_t)tile * 8192;   // 16KB tile, fragment order
    const u16* vp = vFb + (size_t)tile * 8192;
    char* kb = smem + bi*16384;
    char* vb = smem + 32768 + bi*16384;
    int off = threadIdx.x * 8;                   // elements
    #pragma unroll
    for (int i = 0; i < 4; ++i) {
      GLD16(kp + off + i*2048, kb + threadIdx.x*16 + i*4096);
      GLD16(vp + off + i*2048, vb + threadIdx.x*16 + i*4096);
    }
  };

  f32x16 oacc[8];
  #pragma unroll
  for (int ct = 0; ct < 8; ++ct)
    oacc[ct] = (f32x16){0.f,0.f,0.f,0.f,0.f,0.f,0.f,0.f,0.f,0.f,0.f,0.f,0.f,0.f,0.f,0.f};
  float lrun = 0.f;

  STAGE(0, h2);
  __syncthreads();

  for (int it = 0; it < 64; ++it) {
    int cur = it & 1;
    if (it < 63) STAGE(cur ^ 1, 2*(it+1) + h2);   // interleaved halves: L2 lockstep
    const char* kb = smem + cur*16384;
    const char* vb = smem + 32768 + cur*16384;

    // QK^T (swapped): S^T col n=ln, rows m in regs
    f32x16 st = (f32x16){0.f,0.f,0.f,0.f,0.f,0.f,0.f,0.f,0.f,0.f,0.f,0.f,0.f,0.f,0.f,0.f};
    __builtin_amdgcn_s_setprio(1);
    #pragma unroll
    for (int kc = 0; kc < 16; ++kc) {
      bf16x8 kf = *(const bf16x8*)(kb + kc*1024 + lane*16);
      st = __builtin_amdgcn_mfma_f32_32x32x16_bf16(kf, qf[kc], st, 0, 0, 0);
    }
    __builtin_amdgcn_s_setprio(0);

    // no-max softmax
    float p[16];
    #pragma unroll
    for (int r = 0; r < 16; ++r) p[r] = __expf(st[r]);
    lrun += (((p[0]+p[1])+(p[2]+p[3])) + ((p[4]+p[5])+(p[6]+p[7])))
          + (((p[8]+p[9])+(p[10]+p[11])) + ((p[12]+p[13])+(p[14]+p[15])));

    u32 a0 = cvtpk(p[0],  p[1]),  a1 = cvtpk(p[2],  p[3]);
    u32 a2 = cvtpk(p[4],  p[5]),  a3 = cvtpk(p[6],  p[7]);
    u32 a4 = cvtpk(p[8],  p[9]),  a5 = cvtpk(p[10], p[11]);
    u32 a6 = cvtpk(p[12], p[13]), a7 = cvtpk(p[14], p[15]);
    plswap(a0, a2); plswap(a1, a3);          // ks0: m 0..15
    plswap(a4, a6); plswap(a5, a7);          // ks1: m 16..31
    union { u32 u[4]; bf16x8 v; } pa0, pa1;
    pa0.u[0]=a0; pa0.u[1]=a1; pa0.u[2]=a2; pa0.u[3]=a3;
    pa1.u[0]=a4; pa1.u[1]=a5; pa1.u[2]=a6; pa1.u[3]=a7;

    // PV: A=V^T (rows c), B=P^T (cols n) -> O^T
    __builtin_amdgcn_s_setprio(1);
    #pragma unroll
    for (int ks = 0; ks < 2; ++ks) {
      bf16x8 pa = ks ? pa1.v : pa0.v;
      #pragma unroll
      for (int ct = 0; ct < 8; ++ct) {
        bf16x8 vf = *(const bf16x8*)(vb + (ks*8 + ct)*1024 + lane*16);
        oacc[ct] = __builtin_amdgcn_mfma_f32_32x32x16_bf16(vf, pa, oacc[ct], 0, 0, 0);
      }
    }
    __builtin_amdgcn_s_setprio(0);
    __syncthreads();
  }

  lrun += __shfl_xor(lrun, 32);
  if (lane < 32) lsum[((size_t)(h2*NB + b))*NHW + n0 + w*32 + lane] = lrun;

  // ---------------- epilogue: O -> LDS [32 n][256 c] bf16 (XOR swizzle) ----------------
  u16* Ol = (u16*)(smem + w*16384);
  #pragma unroll
  for (int ct = 0; ct < 8; ++ct) {
    u32 c0 = cvtpk(oacc[ct][0],  oacc[ct][1]),  c1 = cvtpk(oacc[ct][2],  oacc[ct][3]);
    u32 c2 = cvtpk(oacc[ct][4],  oacc[ct][5]),  c3 = cvtpk(oacc[ct][6],  oacc[ct][7]);
    u32 c4 = cvtpk(oacc[ct][8],  oacc[ct][9]),  c5 = cvtpk(oacc[ct][10], oacc[ct][11]);
    u32 c6 = cvtpk(oacc[ct][12], oacc[ct][13]), c7 = cvtpk(oacc[ct][14], oacc[ct][15]);
    plswap(c0, c2); plswap(c1, c3);
    plswap(c4, c6); plswap(c5, c7);
    uint4 w0 = {c0, c1, c2, c3};
    uint4 w1 = {c4, c5, c6, c7};
    *(uint4*)(Ol + ln*256 + (((ct*4 + 0 + hl) ^ ln)) * 8) = w0;
    *(uint4*)(Ol + ln*256 + (((ct*4 + 2 + hl) ^ ln)) * 8) = w1;
  }

  // proj: D[n][o] = O[n][c] x W^T[c][o]; W fragment-linear from global (L2-hot)
  f32x16 pacc[8];
  #pragma unroll
  for (int ot = 0; ot < 8; ++ot)
    pacc[ot] = (f32x16){0.f,0.f,0.f,0.f,0.f,0.f,0.f,0.f,0.f,0.f,0.f,0.f,0.f,0.f,0.f,0.f};
  #pragma unroll
  for (int ks = 0; ks < 16; ++ks) {
    bf16x8 af = *(const bf16x8*)(Ol + ln*256 + (((ks*2 + hl) ^ ln)) * 8);
    #pragma unroll
    for (int ot = 0; ot < 8; ++ot) {
      bf16x8 wf = *(const bf16x8*)(wprojF + ((size_t)(ot*16 + ks)*64 + lane) * 8);
      pacc[ot] = __builtin_amdgcn_mfma_f32_32x32x16_bf16(af, wf, pacc[ot], 0, 0, 0);
    }
  }
  // store Praw [n][o] bf16: per r, lanes cover o contiguous (64B) -> coalesced
  u16* Pr = Praw + ((size_t)(h2*NB + b)) * NHW * NC;
  #pragma unroll
  for (int ot = 0; ot < 8; ++ot) {
    int o = ot*32 + ln;
    #pragma unroll
    for (int r = 0; r < 16; ++r) {
      int n = n0 + w*32 + (r & 3) + 8*(r >> 2) + 4*hl;
      Pr[(size_t)n * NC + o] = f2bf(pacc[ot][r]);
    }
  }
}

// ---------------- merge scale: 1/(l0+l1) ----------------
__global__ __launch_bounds__(256) void s_k(const float* __restrict__ lsum,
                                           float* __restrict__ s){
  int i = blockIdx.x * 256 + threadIdx.x;
  s[i] = 1.f / (lsum[i] + lsum[(size_t)NB * NHW + i]);
}

// ---------------- combine: out[b][o][n] = x + bias + s[n]*(P0[n][o]+P1[n][o]) ----------------
// 1024 blocks = 8b x 128 n-tiles of 32. P bf16; LDS transpose [32 n][256 o] f32 (pad 258).
__global__ __launch_bounds__(256) void combine_k(const float* __restrict__ x,
    const u16* __restrict__ P0, const u16* __restrict__ P1,
    const float* __restrict__ s, const float* __restrict__ b_proj,
    float* __restrict__ out){
  __shared__ float T[32 * 258];
  int bid = blockIdx.x;
  int b = bid & 7, nt = bid >> 3;
  int n0c = nt * 32;
  const u16* p0 = P0 + ((size_t)b * NHW + n0c) * NC;
  const u16* p1 = P1 + ((size_t)b * NHW + n0c) * NC;
  int t = threadIdx.x;
  int nl = t >> 3;
  #pragma unroll
  for (int j = 0; j < 4; ++j) {
    int cc = (t & 7) * 8 + j * 64;            // 8 consecutive u16 cols per thread
    uint4 a = *(const uint4*)(p0 + nl*NC + cc);
    uint4 c = *(const uint4*)(p1 + nl*NC + cc);
    float* tp = T + nl*258 + cc;
    tp[0] = bf2f((u16)(a.x & 0xffff)) + bf2f((u16)(c.x & 0xffff));
    tp[1] = bf2f((u16)(a.x >> 16))    + bf2f((u16)(c.x >> 16));
    tp[2] = bf2f((u16)(a.y & 0xffff)) + bf2f((u16)(c.y & 0xffff));
    tp[3] = bf2f((u16)(a.y >> 16))    + bf2f((u16)(c.y >> 16));
    tp[4] = bf2f((u16)(a.z & 0xffff)) + bf2f((u16)(c.z & 0xffff));
    tp[5] = bf2f((u16)(a.z >> 16))    + bf2f((u16)(c.z >> 16));
    tp[6] = bf2f((u16)(a.w & 0xffff)) + bf2f((u16)(c.w & 0xffff));
    tp[7] = bf2f((u16)(a.w >> 16))    + bf2f((u16)(c.w >> 16));
  }
  int n = t & 31, og = t >> 5;
  float sv = s[b*NHW + n0c + n];
  __syncthreads();
  #pragma unroll 4
  for (int pass = 0; pass < 32; ++pass) {
    int o = pass*8 + og;
    size_t base = ((size_t)(b*NC + o))*NHW + n0c + n;
    out[base] = x[base] + b_proj[o] + sv * T[n*258 + o];
  }
}

// ---------------- fallback: R3 fused attention (old layouts) ----------------
__global__ __launch_bounds__(256, 2) void attn_fb_k(const float* __restrict__ x,
    const u16* __restrict__ qT, const u16* __restrict__ kT, const u16* __restrict__ vS,
    const float* __restrict__ w_proj, const float* __restrict__ b_proj,
    float* __restrict__ out){
  __shared__ char smem[73728];
  u16* Klds = (u16*)smem;
  u16* Vlds = (u16*)(smem + 32768);
  float* Olds = (float*)smem;

  int bid = blockIdx.x;
  int wg = ((bid & 7) << 6) | (bid >> 3);
  int b  = wg >> 6;
  int n0 = (wg & 63) << 6;
  int w = threadIdx.x >> 6, lane = threadIdx.x & 63;
  int lo = lane & 15, g = lane >> 4;
  int sw = lo & 7;

  const u16* qTb = qT + (size_t)b * NHW * NC;
  const u16* kTb = kT + (size_t)b * NHW * NC;
  const u16* vSb = vS + (size_t)b * NC * NHW;

  bf16x8 qf[8];
  {
    const u16* qp = qTb + (size_t)(n0 + w*16 + lo) * NC + g*8;
    #pragma unroll
    for (int kc = 0; kc < 8; ++kc) qf[kc] = *(const bf16x8*)(qp + kc*32);
  }

  int koff[8], voff[8];
  #pragma unroll
  for (int i = 0; i < 8; ++i) {
    int o = w*8192 + i*1024 + lane*16;
    int mr = o >> 9;
    int kch = ((o >> 4) & 31) ^ (mr & 7);
    koff[i] = mr*NC + kch*8;
    int cr = o >> 7;
    int vch = ((o >> 4) & 7) ^ (cr & 7);
    voff[i] = cr*NHW + vch*8;
  }

  f32x4 oacc[16];
  #pragma unroll
  for (int i = 0; i < 16; ++i) oacc[i] = (f32x4){0.f,0.f,0.f,0.f};
  float mrun = -1e30f, lrun = 0.f;

  char* Pw = smem + 65536 + w*2048;

  for (int m0 = 0; m0 < NHW; m0 += 64) {
    __syncthreads();
    const u16* kp = kTb + (size_t)m0 * NC;
    const u16* vp = vSb + m0;
    #pragma unroll
    for (int i = 0; i < 8; ++i) {
      GLD16(kp + koff[i], smem + w*8192 + i*1024);
      GLD16(vp + voff[i], smem + 32768 + w*8192 + i*1024);
    }
    __syncthreads();

    f32x4 st[4];
    #pragma unroll
    for (int mt = 0; mt < 4; ++mt) st[mt] = (f32x4){0.f,0.f,0.f,0.f};
    #pragma unroll
    for (int kc = 0; kc < 8; ++kc) {
      #pragma unroll
      for (int mt = 0; mt < 4; ++mt) {
        int ch = (kc*4 + g) ^ sw;
        bf16x8 kf = *(const bf16x8*)(Klds + (mt*16 + lo)*NC + ch*8);
        st[mt] = __builtin_amdgcn_mfma_f32_16x16x32_bf16(kf, qf[kc], st[mt], 0, 0, 0);
      }
    }

    float pmax = -1e30f;
    #pragma unroll
    for (int mt = 0; mt < 4; ++mt)
      #pragma unroll
      for (int r = 0; r < 4; ++r) pmax = fmaxf(pmax, st[mt][r]);
    pmax = fmaxf(pmax, __shfl_xor(pmax, 16));
    pmax = fmaxf(pmax, __shfl_xor(pmax, 32));

    if (!__all(pmax - mrun <= 8.f)) {
      float mnew = fmaxf(mrun, pmax);
      float corr = __expf(mrun - mnew);
      mrun = mnew;
      lrun *= corr;
      float c0 = __shfl(corr, 4*g+0), c1 = __shfl(corr, 4*g+1);
      float c2 = __shfl(corr, 4*g+2), c3 = __shfl(corr, 4*g+3);
      #pragma unroll
      for (int ct = 0; ct < 16; ++ct) {
        oacc[ct][0] *= c0; oacc[ct][1] *= c1; oacc[ct][2] *= c2; oacc[ct][3] *= c3;
      }
    }

    float psum = 0.f;
    #pragma unroll
    for (int mt = 0; mt < 4; ++mt) {
      float p0 = __expf(st[mt][0] - mrun);
      float p1 = __expf(st[mt][1] - mrun);
      float p2 = __expf(st[mt][2] - mrun);
      float p3 = __expf(st[mt][3] - mrun);
      psum += (p0 + p1) + (p2 + p3);
      uint2 pk = { pack2(p0, p1), pack2(p2, p3) };
      *(uint2*)(Pw + lo*128 + ((((2*mt + (g>>1)) ^ sw)) << 4) + ((g&1) << 3)) = pk;
    }
    psum += __shfl_xor(psum, 16);
    psum += __shfl_xor(psum, 32);
    lrun += psum;

    #pragma unroll
    for (int ks = 0; ks < 2; ++ks) {
      bf16x8 pa = *(const bf16x8*)(Pw + lo*128 + (((ks*4 + g) ^ sw) << 4));
      #pragma unroll
      for (int ct = 0; ct < 16; ++ct) {
        int ch = (ks*4 + g) ^ sw;
        bf16x8 vf = *(const bf16x8*)(Vlds + (ct*16 + lo)*64 + ch*8);
        oacc[ct] = __builtin_amdgcn_mfma_f32_16x16x32_bf16(pa, vf, oacc[ct], 0, 0, 0);
      }
    }
  }

  __syncthreads();
  float linv = 1.f / lrun;
  float l0 = __shfl(linv, 4*g+0), l1 = __shfl(linv, 4*g+1);
  float l2 = __shfl(linv, 4*g+2), l3 = __shfl(linv, 4*g+3);
  float* Ow = Olds + w*4096;
  #pragma unroll
  for (int ct = 0; ct < 16; ++ct) {
    int col = ct*16 + lo;
    Ow[(4*g+0)*256 + col] = oacc[ct][0] * l0;
    Ow[(4*g+1)*256 + col] = oacc[ct][1] * l1;
    Ow[(4*g+2)*256 + col] = oacc[ct][2] * l2;
    Ow[(4*g+3)*256 + col] = oacc[ct][3] * l3;
  }

  f32x4 pacc[16];
  #pragma unroll
  for (int i = 0; i < 16; ++i) pacc[i] = (f32x4){0.f,0.f,0.f,0.f};
  #pragma unroll
  for (int ks = 0; ks < 8; ++ks) {
    const float* ap = Ow + lo*256 + ks*32 + g*8;
    float4 a0 = *(const float4*)ap;
    float4 a1 = *(const float4*)(ap + 4);
    union { u16 h[8]; bf16x8 v; } au;
    au.h[0]=f2bf(a0.x); au.h[1]=f2bf(a0.y); au.h[2]=f2bf(a0.z); au.h[3]=f2bf(a0.w);
    au.h[4]=f2bf(a1.x); au.h[5]=f2bf(a1.y); au.h[6]=f2bf(a1.z); au.h[7]=f2bf(a1.w);
    bf16x8 af = au.v;
    #pragma unroll
    for (int ot = 0; ot < 16; ++ot) {
      const float* wp = w_proj + (size_t)(ot*16 + lo)*NC + ks*32 + g*8;
      float4 b0 = *(const float4*)wp;
      float4 b1 = *(const float4*)(wp + 4);
      union { u16 h[8]; bf16x8 v; } bu;
      bu.h[0]=f2bf(b0.x); bu.h[1]=f2bf(b0.y); bu.h[2]=f2bf(b0.z); bu.h[3]=f2bf(b0.w);
      bu.h[4]=f2bf(b1.x); bu.h[5]=f2bf(b1.y); bu.h[6]=f2bf(b1.z); bu.h[7]=f2bf(b1.w);
      pacc[ot] = __builtin_amdgcn_mfma_f32_16x16x32_bf16(af, bu.v, pacc[ot], 0, 0, 0);
    }
  }

  int nr = n0 + w*16 + 4*g;
  #pragma unroll
  for (int ot = 0; ot < 16; ++ot) {
    int o = ot*16 + lo;
    float bp = b_proj[o];
    size_t base = ((size_t)(b*NC + o)) * NHW + nr;
    float4 xr = *(const float4*)(x + base);
    float4 ov = { pacc[ot][0] + bp + xr.x, pacc[ot][1] + bp + xr.y,
                  pacc[ot][2] + bp + xr.z, pacc[ot][3] + bp + xr.w };
    *(float4*)(out + base) = ov;
  }
}

extern "C" void kernel_launch(void* const* d_in, const int* in_sizes, int n_in,
                              void* d_out, int out_size, void* d_ws, size_t ws_size,
                              hipStream_t stream) {
  const float* x      = (const float*)d_in[0];
  const float* gamma  = (const float*)d_in[1];
  const float* beta   = (const float*)d_in[2];
  const float* w_qkv  = (const float*)d_in[3];
  const float* b_qkv  = (const float*)d_in[4];
  const float* w_proj = (const float*)d_in[5];
  const float* b_proj = (const float*)d_in[6];
  float* out = (float*)d_out;

  char* p = (char*)d_ws;
  float* stats = (float*)p;                           // 512 f
  float* coef  = stats + 2 * NB * NG;                 // 4096 f
  u16* qT = (u16*)(p + 18432);                        // [b][n][c] 16MB
  u16* kF = qT + (size_t)NB * NHW * NC;               // K fragment-linear 16MB
  u16* vF = kF + (size_t)NB * NHW * NC;               // V fragment-linear 16MB
  u16* wqbf = vF + (size_t)NB * NC * NHW;             // qkv W bf16 swizzled, 384KB
  u16* wprojF = wqbf + 3 * NC * NC;                   // proj W fragment-linear, 128KB
  size_t base_end = 18432 + (size_t)3 * NB * NHW * NC * 2
                  + (size_t)3 * NC * NC * 2 + (size_t)NC * NC * 2;
  u16* Praw = (u16*)(p + base_end);                   // [2][b][n][o] bf16, 33.5MB
  float* lsum = (float*)(p + base_end + (size_t)2*NB*NC*NHW*2);   // [2][b][n]
  float* sbuf = lsum + (size_t)2*NB*NHW;
  size_t need_split = base_end + (size_t)2*NB*NC*NHW*2 + (size_t)3*NB*NHW*4;

  gn_stats_k<<<NB * NG, 256, 0, stream>>>(x, stats);
  gn_coef_k<<<(NB * NC + 255) / 256, 256, 0, stream>>>(stats, gamma, beta, coef);
  if (ws_size >= need_split) {
    cvtw2_k<<<NC * NC / 256, 256, 0, stream>>>(w_proj, wprojF);
    cvtw_k<<<3 * NC * NC / 256, 256, 0, stream>>>(w_qkv, wqbf);
    qkv_mfma_k<<<512, 256, 0, stream>>>(x, coef, wqbf, b_qkv, qT, kF, vF);
    attn_split_k<<<512, 256, 0, stream>>>(qT, kF, vF, wprojF, Praw, lsum);
    s_k<<<NB * NHW / 256, 256, 0, stream>>>(lsum, sbuf);
    combine_k<<<1024, 256, 0, stream>>>(x, Praw, Praw + (size_t)NB*NC*NHW,
                                        sbuf, b_proj, out);
  } else {
    qkv_scalar_k<<<NB * 16 * 48, 256, 0, stream>>>(x, coef, w_qkv, b_qkv, qT, kF, vF);
    attn_fb_k<<<512, 256, 0, stream>>>(x, qT, kF, vF, w_proj, b_proj, out);
  }
}

// Round 11
// 221.152 us; speedup vs baseline: 1.1808x; 1.1808x over previous
//
#include <hip/hip_runtime.h>
#include <stdint.h>

#define NB 8
#define NC 256
#define NHW 4096
#define NG 32
#define GELEMS (8*NHW)
#define EPS 1e-5f

typedef unsigned short u16;
typedef unsigned int u32;
typedef __attribute__((ext_vector_type(8))) short bf16x8;
typedef __attribute__((ext_vector_type(4))) float f32x4;
typedef __attribute__((ext_vector_type(16))) float f32x16;

__device__ __forceinline__ float bf2f(u16 u){ return __uint_as_float((u32)u << 16); }
__device__ __forceinline__ u16 f2bf(float f){
  u32 i = __float_as_uint(f);
  u32 r = i + 0x7fffu + ((i >> 16) & 1u);   // RNE
  return (u16)(r >> 16);
}
__device__ __forceinline__ u32 pack2(float a, float b){
  return (u32)f2bf(a) | ((u32)f2bf(b) << 16);
}
__device__ __forceinline__ u32 cvtpk(float lo, float hi){
  u32 r;
  asm("v_cvt_pk_bf16_f32 %0, %1, %2" : "=v"(r) : "v"(lo), "v"(hi));
  return r;
}
__device__ __forceinline__ void plswap(u32 &a, u32 &b){
  asm volatile("v_permlane32_swap_b32 %0, %1" : "+v"(a), "+v"(b));
}

#define GLD16(g, l) __builtin_amdgcn_global_load_lds( \
    (const __attribute__((address_space(1))) u32*)(g), \
    (__attribute__((address_space(3))) u32*)(l), 16, 0, 0)

// ---------------- GroupNorm statistics ----------------
__global__ __launch_bounds__(256) void gn_stats_k(const float* __restrict__ x,
                                                  float* __restrict__ stats){
  int bg = blockIdx.x;
  const float* xp = x + (size_t)bg * GELEMS;
  float s = 0.f, s2 = 0.f;
  for (int i = threadIdx.x * 4; i < GELEMS; i += 256 * 4) {
    float4 v = *(const float4*)(xp + i);
    s  += v.x + v.y + v.z + v.w;
    s2 += v.x*v.x + v.y*v.y + v.z*v.z + v.w*v.w;
  }
  #pragma unroll
  for (int off = 32; off; off >>= 1) { s += __shfl_xor(s, off); s2 += __shfl_xor(s2, off); }
  __shared__ float rs[4], rs2[4];
  int w = threadIdx.x >> 6;
  if ((threadIdx.x & 63) == 0) { rs[w] = s; rs2[w] = s2; }
  __syncthreads();
  if (threadIdx.x == 0) {
    float ts = rs[0]+rs[1]+rs[2]+rs[3], t2 = rs2[0]+rs2[1]+rs2[2]+rs2[3];
    float mean = ts * (1.f/GELEMS);
    float var  = t2 * (1.f/GELEMS) - mean*mean;
    stats[2*bg]   = mean;
    stats[2*bg+1] = rsqrtf(var + EPS);
  }
}

__global__ __launch_bounds__(256) void gn_coef_k(const float* __restrict__ stats,
                                                 const float* __restrict__ gamma,
                                                 const float* __restrict__ beta,
                                                 float* __restrict__ coef){
  int i = blockIdx.x * 256 + threadIdx.x;
  if (i >= NB*NC) return;
  int b = i >> 8, c = i & 255;
  float mean = stats[2*(b*NG + (c>>3))];
  float rstd = stats[2*(b*NG + (c>>3)) + 1];
  float sc = gamma[c] * rstd;
  coef[2*i]   = sc;
  coef[2*i+1] = beta[c] - mean * sc;
}

__global__ __launch_bounds__(256) void cvtw_k(const float* __restrict__ w,
                                              u16* __restrict__ wbf){
  int i = blockIdx.x * 256 + threadIdx.x;
  wbf[i] = f2bf(w[i]);
}

// fragment-linear proj W for 32x32 MFMA B-operand: chunk (ot*16+ks)*64+l holds
// W^T[c = ks*16+(l>>5)*8 + e][o = ot*32+(l&31)]
__global__ __launch_bounds__(256) void cvtw2_k(const float* __restrict__ w,
                                               u16* __restrict__ wf){
  int i = blockIdx.x * 256 + threadIdx.x;     // 65536
  int e = i & 7, chunk = i >> 3;
  int l = chunk & 63, ks = (chunk >> 6) & 15, ot = chunk >> 10;
  int c = ks*16 + (l>>5)*8 + e;
  int o = ot*32 + (l&31);
  wf[i] = f2bf(w[o*NC + c]);
}

// -------- MFMA fused GN + QKV --------
// Q -> [n][c] bf16 (pre-scaled 1/16).
// K -> fragment-linear: elem(m,c) at ((t*16+kcc)*64 + l)*8 + e,
//      t=m>>5, kcc=c>>4, l=(m&31)+32*((c>>3)&1), e=c&7.
// V -> fragment-linear: elem(c,m) at ((t*16+cv)*64 + l)*8 + e,
//      t=m>>5, cv=((c>>5)&7)+8*((m&31)>>4), l=(c&31)+32*((m>>3)&1), e=m&7.
__global__ __launch_bounds__(256, 2) void qkv_mfma_k(const float* __restrict__ x,
    const float* __restrict__ coef, const u16* __restrict__ wqbf,
    const float* __restrict__ b_qkv,
    u16* __restrict__ qT, u16* __restrict__ kF, u16* __restrict__ vF){
  __shared__ u16 Wbuf[2][4096];              // [16][256] bf16, chunk^=(row&7)

  int bid = blockIdx.x;
  int wg = ((bid & 7) << 6) | (bid >> 3);    // XCD swizzle: batch b -> XCD b
  int b  = wg >> 6;
  int n0 = (wg & 63) << 6;
  int w = threadIdx.x >> 6, lane = threadIdx.x & 63;
  int lo = lane & 15, g = lane >> 4;
  int n = n0 + w*16 + lo;

  int row1 = w*2 + (lane >> 5);
  int sxor = ((lane & 31) ^ (row1 & 7)) * 8;
  int src1 = row1 * 256 + sxor;
  int src2 = (row1 + 8) * 256 + sxor;

  auto STAGE = [&](int bufi, int ot) {
    const u16* src = wqbf + ot * 4096;
    GLD16(src + src1, &Wbuf[bufi][w * 512]);
    GLD16(src + src2, &Wbuf[bufi][2048 + w * 512]);
  };

  STAGE(0, 0);

  bf16x8 hf[8];
  {
    const float* xb = x + (size_t)b * NC * NHW + n;
    const float* cf = coef + b * 512;
    #pragma unroll
    for (int kc = 0; kc < 8; ++kc) {
      union { u32 u[4]; bf16x8 v; } hu;
      #pragma unroll
      for (int p = 0; p < 4; ++p) {
        int c = kc*32 + g*8 + p*2;
        float2 s0 = *(const float2*)(cf + 2*c);
        float2 s1 = *(const float2*)(cf + 2*c + 2);
        float f0 = xb[(size_t)c * NHW]     * s0.x + s0.y;
        float f1 = xb[(size_t)(c+1) * NHW] * s1.x + s1.y;
        hu.u[p] = pack2(f0, f1);
      }
      hf[kc] = hu.v;
    }
  }

  u16* qrow = qT + ((size_t)(b * NHW + n)) * NC;
  u16* kFb = kF + (size_t)b * NHW * NC;
  u16* vFb = vF + (size_t)b * NHW * NC;

  for (int ot = 0; ot < 48; ++ot) {
    __syncthreads();
    if (ot < 47) STAGE((ot + 1) & 1, ot + 1);
    const u16* Wl = Wbuf[ot & 1];
    int sw = lo & 7;
    f32x4 acc = (f32x4){0.f, 0.f, 0.f, 0.f};

    if (ot < 32) {
      // C[o][j]: o = ot*16+4g+r, j (pixel) = lo
      #pragma unroll
      for (int kc = 0; kc < 8; ++kc) {
        bf16x8 wf = *(const bf16x8*)(Wl + lo*256 + ((kc*4 + g) ^ sw) * 8);
        acc = __builtin_amdgcn_mfma_f32_16x16x32_bf16(wf, hf[kc], acc, 0, 0, 0);
      }
      float4 bq = *(const float4*)(b_qkv + ot*16 + 4*g);
      float v0 = acc[0]+bq.x, v1 = acc[1]+bq.y, v2 = acc[2]+bq.z, v3 = acc[3]+bq.w;
      if (ot < 16) {                          // Q, scaled
        v0 *= 0.0625f; v1 *= 0.0625f; v2 *= 0.0625f; v3 *= 0.0625f;
        uint2 st = { pack2(v0, v1), pack2(v2, v3) };
        *(uint2*)(qrow + ot*16 + 4*g) = st;
      } else {                                // K fragment-linear: c = (ot-16)*16+4g+r, m = n
        uint2 st = { pack2(v0, v1), pack2(v2, v3) };
        int cb = (ot-16)*16 + 4*g;
        int l = (n & 31) + 32*((cb >> 3) & 1);
        size_t addr = (((size_t)(n >> 5)*16 + (ot-16))*64 + l)*8 + (cb & 7);
        *(uint2*)(kFb + addr) = st;
      }
    } else {
      // swapped: C[j][o]: j (pixel m) = 4g+r local, o (channel c) = (ot-32)*16+lo
      #pragma unroll
      for (int kc = 0; kc < 8; ++kc) {
        bf16x8 wf = *(const bf16x8*)(Wl + lo*256 + ((kc*4 + g) ^ sw) * 8);
        acc = __builtin_amdgcn_mfma_f32_16x16x32_bf16(hf[kc], wf, acc, 0, 0, 0);
      }
      int oc = (ot - 32) * 16 + lo;           // channel c
      float bv = b_qkv[512 + oc];
      uint2 st = { pack2(acc[0]+bv, acc[1]+bv), pack2(acc[2]+bv, acc[3]+bv) };
      int m = n0 + w*16 + 4*g;                // pixel base (4 consecutive m in elems)
      int cv = ((oc >> 5) & 7) + 8*(w & 1);
      int l = (oc & 31) + 32*((w*2 + (g >> 1)) & 1);
      size_t addr = (((size_t)(m >> 5)*16 + cv)*64 + l)*8 + ((4*g) & 7);
      *(uint2*)(vFb + addr) = st;
    }
  }
}

// ---------------- scalar qkv fallback (old layouts) ----------------
__global__ __launch_bounds__(256) void qkv_scalar_k(const float* __restrict__ x,
                                             const float* __restrict__ coef,
                                             const float* __restrict__ w_qkv,
                                             const float* __restrict__ b_qkv,
                                             u16* __restrict__ qT, u16* __restrict__ kT,
                                             u16* __restrict__ vS){
  int idx0 = blockIdx.x;
  int idx = (idx0 >> 3) + (idx0 & 7) * 768;
  int og = idx % 48;
  int t  = idx / 48;
  int nc = t & 15;
  int b  = t >> 4;
  int n  = nc * 256 + threadIdx.x;
  const float* xb = x + (size_t)b * NC * NHW + n;
  const float* cf = coef + b * NC * 2;
  int ob = og * 16;
  float acc[16];
  #pragma unroll
  for (int j = 0; j < 16; ++j) acc[j] = b_qkv[ob + j];
  for (int c = 0; c < NC; ++c) {
    float h = xb[(size_t)c * NHW] * cf[2*c] + cf[2*c+1];
    const float* wr = w_qkv + (size_t)ob * NC + c;
    #pragma unroll
    for (int j = 0; j < 16; ++j) acc[j] += h * wr[(size_t)j * NC];
  }
  if (ob < 512) {
    float sc = (ob < 256) ? 0.0625f : 1.0f;
    union { u16 h[16]; uint4 q[2]; } u;
    #pragma unroll
    for (int j = 0; j < 16; ++j) u.h[j] = f2bf(acc[j] * sc);
    u16* p = (ob < 256) ? (qT + ((size_t)(b*NHW + n))*NC + ob)
                        : (kT + ((size_t)(b*NHW + n))*NC + (ob - 256));
    *(uint4*)p = u.q[0];
    *(uint4*)(p + 8) = u.q[1];
  } else {
    u16* p = vS + ((size_t)(b*NC) + (ob - 512)) * NHW + n;
    #pragma unroll
    for (int j = 0; j < 16; ++j) p[(size_t)j * NHW] = f2bf(acc[j]);
  }
}

// ========== split-KV flash attention, 32x32 MFMA, fragment-linear K/V (R8 cfg) ==========
// 512 blocks = (b=8) x (rowblk=32) x (half=2); 4 waves x 32 rows; 2 blocks/CU.
// Staging = pure linear 16KB copy (coalesced); LDS reads contiguous 1KB (0 conflicts).
// No-max softmax; P in-register (cvt_pk + permlane32_swap); bf16 Praw. NO setprio (R10 lesson).
__global__ __launch_bounds__(256, 2) void attn_split_k(
    const u16* __restrict__ qT, const u16* __restrict__ kF, const u16* __restrict__ vF,
    const u16* __restrict__ wprojF, u16* __restrict__ Praw, float* __restrict__ lsum){
  __shared__ char smem[65536];
  // Kbuf[2] 16KB at 0; Vbuf[2] 16KB at 32768. Epilogue alias: per-wave O 16KB at w*16384.

  int bid = blockIdx.x;
  int b = bid & 7;                           // batch -> XCD
  int u = bid >> 3;
  int rb = u >> 1, h2 = u & 1;
  int n0 = rb << 7;
  int w = threadIdx.x >> 6, lane = threadIdx.x & 63;
  int ln = lane & 31, hl = lane >> 5;

  const u16* qTb = qT + (size_t)b * NHW * NC;
  const u16* kFb = kF + (size_t)b * NHW * NC;
  const u16* vFb = vF + (size_t)b * NHW * NC;

  int nrow = n0 + w*32 + ln;
  bf16x8 qf[16];
  {
    const u16* qp = qTb + (size_t)nrow * NC + hl*8;
    #pragma unroll
    for (int kc = 0; kc < 16; ++kc) qf[kc] = *(const bf16x8*)(qp + kc*16);
  }

  auto STAGE = [&](int bi, int tile){
    const u16* kp = kFb + (size_t)tile * 8192;   // 16KB tile, fragment order
    const u16* vp = vFb + (size_t)tile * 8192;
    char* kb = smem + bi*16384;
    char* vb = smem + 32768 + bi*16384;
    int off = threadIdx.x * 8;                   // elements
    #pragma unroll
    for (int i = 0; i < 4; ++i) {
      GLD16(kp + off + i*2048, kb + threadIdx.x*16 + i*4096);
      GLD16(vp + off + i*2048, vb + threadIdx.x*16 + i*4096);
    }
  };

  f32x16 oacc[8];
  #pragma unroll
  for (int ct = 0; ct < 8; ++ct)
    oacc[ct] = (f32x16){0.f,0.f,0.f,0.f,0.f,0.f,0.f,0.f,0.f,0.f,0.f,0.f,0.f,0.f,0.f,0.f};
  float lrun = 0.f;

  STAGE(0, h2);
  __syncthreads();

  for (int it = 0; it < 64; ++it) {
    int cur = it & 1;
    if (it < 63) STAGE(cur ^ 1, 2*(it+1) + h2);   // interleaved halves: L2 lockstep
    const char* kb = smem + cur*16384;
    const char* vb = smem + 32768 + cur*16384;

    // QK^T (swapped): S^T col n=ln, rows m in regs
    f32x16 st = (f32x16){0.f,0.f,0.f,0.f,0.f,0.f,0.f,0.f,0.f,0.f,0.f,0.f,0.f,0.f,0.f,0.f};
    #pragma unroll
    for (int kc = 0; kc < 16; ++kc) {
      bf16x8 kf = *(const bf16x8*)(kb + kc*1024 + lane*16);
      st = __builtin_amdgcn_mfma_f32_32x32x16_bf16(kf, qf[kc], st, 0, 0, 0);
    }

    // no-max softmax
    float p[16];
    #pragma unroll
    for (int r = 0; r < 16; ++r) p[r] = __expf(st[r]);
    lrun += (((p[0]+p[1])+(p[2]+p[3])) + ((p[4]+p[5])+(p[6]+p[7])))
          + (((p[8]+p[9])+(p[10]+p[11])) + ((p[12]+p[13])+(p[14]+p[15])));

    u32 a0 = cvtpk(p[0],  p[1]),  a1 = cvtpk(p[2],  p[3]);
    u32 a2 = cvtpk(p[4],  p[5]),  a3 = cvtpk(p[6],  p[7]);
    u32 a4 = cvtpk(p[8],  p[9]),  a5 = cvtpk(p[10], p[11]);
    u32 a6 = cvtpk(p[12], p[13]), a7 = cvtpk(p[14], p[15]);
    plswap(a0, a2); plswap(a1, a3);          // ks0: m 0..15
    plswap(a4, a6); plswap(a5, a7);          // ks1: m 16..31
    union { u32 u[4]; bf16x8 v; } pa0, pa1;
    pa0.u[0]=a0; pa0.u[1]=a1; pa0.u[2]=a2; pa0.u[3]=a3;
    pa1.u[0]=a4; pa1.u[1]=a5; pa1.u[2]=a6; pa1.u[3]=a7;

    // PV: A=V^T (rows c), B=P^T (cols n) -> O^T
    #pragma unroll
    for (int ks = 0; ks < 2; ++ks) {
      bf16x8 pa = ks ? pa1.v : pa0.v;
      #pragma unroll
      for (int ct = 0; ct < 8; ++ct) {
        bf16x8 vf = *(const bf16x8*)(vb + (ks*8 + ct)*1024 + lane*16);
        oacc[ct] = __builtin_amdgcn_mfma_f32_32x32x16_bf16(vf, pa, oacc[ct], 0, 0, 0);
      }
    }
    __syncthreads();
  }

  lrun += __shfl_xor(lrun, 32);
  if (lane < 32) lsum[((size_t)(h2*NB + b))*NHW + n0 + w*32 + lane] = lrun;

  // ---------------- epilogue: O -> LDS [32 n][256 c] bf16 (XOR swizzle) ----------------
  u16* Ol = (u16*)(smem + w*16384);
  #pragma unroll
  for (int ct = 0; ct < 8; ++ct) {
    u32 c0 = cvtpk(oacc[ct][0],  oacc[ct][1]),  c1 = cvtpk(oacc[ct][2],  oacc[ct][3]);
    u32 c2 = cvtpk(oacc[ct][4],  oacc[ct][5]),  c3 = cvtpk(oacc[ct][6],  oacc[ct][7]);
    u32 c4 = cvtpk(oacc[ct][8],  oacc[ct][9]),  c5 = cvtpk(oacc[ct][10], oacc[ct][11]);
    u32 c6 = cvtpk(oacc[ct][12], oacc[ct][13]), c7 = cvtpk(oacc[ct][14], oacc[ct][15]);
    plswap(c0, c2); plswap(c1, c3);
    plswap(c4, c6); plswap(c5, c7);
    uint4 w0 = {c0, c1, c2, c3};
    uint4 w1 = {c4, c5, c6, c7};
    *(uint4*)(Ol + ln*256 + (((ct*4 + 0 + hl) ^ ln)) * 8) = w0;
    *(uint4*)(Ol + ln*256 + (((ct*4 + 2 + hl) ^ ln)) * 8) = w1;
  }

  // proj: D[n][o] = O[n][c] x W^T[c][o]; W fragment-linear from global (L2-hot)
  f32x16 pacc[8];
  #pragma unroll
  for (int ot = 0; ot < 8; ++ot)
    pacc[ot] = (f32x16){0.f,0.f,0.f,0.f,0.f,0.f,0.f,0.f,0.f,0.f,0.f,0.f,0.f,0.f,0.f,0.f};
  #pragma unroll
  for (int ks = 0; ks < 16; ++ks) {
    bf16x8 af = *(const bf16x8*)(Ol + ln*256 + (((ks*2 + hl) ^ ln)) * 8);
    #pragma unroll
    for (int ot = 0; ot < 8; ++ot) {
      bf16x8 wf = *(const bf16x8*)(wprojF + ((size_t)(ot*16 + ks)*64 + lane) * 8);
      pacc[ot] = __builtin_amdgcn_mfma_f32_32x32x16_bf16(af, wf, pacc[ot], 0, 0, 0);
    }
  }
  // store Praw [n][o] bf16: per r, lanes cover o contiguous (64B) -> coalesced
  u16* Pr = Praw + ((size_t)(h2*NB + b)) * NHW * NC;
  #pragma unroll
  for (int ot = 0; ot < 8; ++ot) {
    int o = ot*32 + ln;
    #pragma unroll
    for (int r = 0; r < 16; ++r) {
      int n = n0 + w*32 + (r & 3) + 8*(r >> 2) + 4*hl;
      Pr[(size_t)n * NC + o] = f2bf(pacc[ot][r]);
    }
  }
}

// ---------------- merge scale: 1/(l0+l1) ----------------
__global__ __launch_bounds__(256) void s_k(const float* __restrict__ lsum,
                                           float* __restrict__ s){
  int i = blockIdx.x * 256 + threadIdx.x;
  s[i] = 1.f / (lsum[i] + lsum[(size_t)NB * NHW + i]);
}

// ---------------- combine: out[b][o][n] = x + bias + s[n]*(P0[n][o]+P1[n][o]) ----------------
// 1024 blocks = 8b x 128 n-tiles of 32. P bf16; LDS transpose [32 n][256 o] f32 (pad 258).
__global__ __launch_bounds__(256) void combine_k(const float* __restrict__ x,
    const u16* __restrict__ P0, const u16* __restrict__ P1,
    const float* __restrict__ s, const float* __restrict__ b_proj,
    float* __restrict__ out){
  __shared__ float T[32 * 258];
  int bid = blockIdx.x;
  int b = bid & 7, nt = bid >> 3;
  int n0c = nt * 32;
  const u16* p0 = P0 + ((size_t)b * NHW + n0c) * NC;
  const u16* p1 = P1 + ((size_t)b * NHW + n0c) * NC;
  int t = threadIdx.x;
  int nl = t >> 3;
  #pragma unroll
  for (int j = 0; j < 4; ++j) {
    int cc = (t & 7) * 8 + j * 64;            // 8 consecutive u16 cols per thread
    uint4 a = *(const uint4*)(p0 + nl*NC + cc);
    uint4 c = *(const uint4*)(p1 + nl*NC + cc);
    float* tp = T + nl*258 + cc;
    tp[0] = bf2f((u16)(a.x & 0xffff)) + bf2f((u16)(c.x & 0xffff));
    tp[1] = bf2f((u16)(a.x >> 16))    + bf2f((u16)(c.x >> 16));
    tp[2] = bf2f((u16)(a.y & 0xffff)) + bf2f((u16)(c.y & 0xffff));
    tp[3] = bf2f((u16)(a.y >> 16))    + bf2f((u16)(c.y >> 16));
    tp[4] = bf2f((u16)(a.z & 0xffff)) + bf2f((u16)(c.z & 0xffff));
    tp[5] = bf2f((u16)(a.z >> 16))    + bf2f((u16)(c.z >> 16));
    tp[6] = bf2f((u16)(a.w & 0xffff)) + bf2f((u16)(c.w & 0xffff));
    tp[7] = bf2f((u16)(a.w >> 16))    + bf2f((u16)(c.w >> 16));
  }
  int n = t & 31, og = t >> 5;
  float sv = s[b*NHW + n0c + n];
  __syncthreads();
  #pragma unroll 4
  for (int pass = 0; pass < 32; ++pass) {
    int o = pass*8 + og;
    size_t base = ((size_t)(b*NC + o))*NHW + n0c + n;
    out[base] = x[base] + b_proj[o] + sv * T[n*258 + o];
  }
}

// ---------------- fallback: R3 fused attention (old layouts) ----------------
__global__ __launch_bounds__(256, 2) void attn_fb_k(const float* __restrict__ x,
    const u16* __restrict__ qT, const u16* __restrict__ kT, const u16* __restrict__ vS,
    const float* __restrict__ w_proj, const float* __restrict__ b_proj,
    float* __restrict__ out){
  __shared__ char smem[73728];
  u16* Klds = (u16*)smem;
  u16* Vlds = (u16*)(smem + 32768);
  float* Olds = (float*)smem;

  int bid = blockIdx.x;
  int wg = ((bid & 7) << 6) | (bid >> 3);
  int b  = wg >> 6;
  int n0 = (wg & 63) << 6;
  int w = threadIdx.x >> 6, lane = threadIdx.x & 63;
  int lo = lane & 15, g = lane >> 4;
  int sw = lo & 7;

  const u16* qTb = qT + (size_t)b * NHW * NC;
  const u16* kTb = kT + (size_t)b * NHW * NC;
  const u16* vSb = vS + (size_t)b * NC * NHW;

  bf16x8 qf[8];
  {
    const u16* qp = qTb + (size_t)(n0 + w*16 + lo) * NC + g*8;
    #pragma unroll
    for (int kc = 0; kc < 8; ++kc) qf[kc] = *(const bf16x8*)(qp + kc*32);
  }

  int koff[8], voff[8];
  #pragma unroll
  for (int i = 0; i < 8; ++i) {
    int o = w*8192 + i*1024 + lane*16;
    int mr = o >> 9;
    int kch = ((o >> 4) & 31) ^ (mr & 7);
    koff[i] = mr*NC + kch*8;
    int cr = o >> 7;
    int vch = ((o >> 4) & 7) ^ (cr & 7);
    voff[i] = cr*NHW + vch*8;
  }

  f32x4 oacc[16];
  #pragma unroll
  for (int i = 0; i < 16; ++i) oacc[i] = (f32x4){0.f,0.f,0.f,0.f};
  float mrun = -1e30f, lrun = 0.f;

  char* Pw = smem + 65536 + w*2048;

  for (int m0 = 0; m0 < NHW; m0 += 64) {
    __syncthreads();
    const u16* kp = kTb + (size_t)m0 * NC;
    const u16* vp = vSb + m0;
    #pragma unroll
    for (int i = 0; i < 8; ++i) {
      GLD16(kp + koff[i], smem + w*8192 + i*1024);
      GLD16(vp + voff[i], smem + 32768 + w*8192 + i*1024);
    }
    __syncthreads();

    f32x4 st[4];
    #pragma unroll
    for (int mt = 0; mt < 4; ++mt) st[mt] = (f32x4){0.f,0.f,0.f,0.f};
    #pragma unroll
    for (int kc = 0; kc < 8; ++kc) {
      #pragma unroll
      for (int mt = 0; mt < 4; ++mt) {
        int ch = (kc*4 + g) ^ sw;
        bf16x8 kf = *(const bf16x8*)(Klds + (mt*16 + lo)*NC + ch*8);
        st[mt] = __builtin_amdgcn_mfma_f32_16x16x32_bf16(kf, qf[kc], st[mt], 0, 0, 0);
      }
    }

    float pmax = -1e30f;
    #pragma unroll
    for (int mt = 0; mt < 4; ++mt)
      #pragma unroll
      for (int r = 0; r < 4; ++r) pmax = fmaxf(pmax, st[mt][r]);
    pmax = fmaxf(pmax, __shfl_xor(pmax, 16));
    pmax = fmaxf(pmax, __shfl_xor(pmax, 32));

    if (!__all(pmax - mrun <= 8.f)) {
      float mnew = fmaxf(mrun, pmax);
      float corr = __expf(mrun - mnew);
      mrun = mnew;
      lrun *= corr;
      float c0 = __shfl(corr, 4*g+0), c1 = __shfl(corr, 4*g+1);
      float c2 = __shfl(corr, 4*g+2), c3 = __shfl(corr, 4*g+3);
      #pragma unroll
      for (int ct = 0; ct < 16; ++ct) {
        oacc[ct][0] *= c0; oacc[ct][1] *= c1; oacc[ct][2] *= c2; oacc[ct][3] *= c3;
      }
    }

    float psum = 0.f;
    #pragma unroll
    for (int mt = 0; mt < 4; ++mt) {
      float p0 = __expf(st[mt][0] - mrun);
      float p1 = __expf(st[mt][1] - mrun);
      float p2 = __expf(st[mt][2] - mrun);
      float p3 = __expf(st[mt][3] - mrun);
      psum += (p0 + p1) + (p2 + p3);
      uint2 pk = { pack2(p0, p1), pack2(p2, p3) };
      *(uint2*)(Pw + lo*128 + ((((2*mt + (g>>1)) ^ sw)) << 4) + ((g&1) << 3)) = pk;
    }
    psum += __shfl_xor(psum, 16);
    psum += __shfl_xor(psum, 32);
    lrun += psum;

    #pragma unroll
    for (int ks = 0; ks < 2; ++ks) {
      bf16x8 pa = *(const bf16x8*)(Pw + lo*128 + (((ks*4 + g) ^ sw) << 4));
      #pragma unroll
      for (int ct = 0; ct < 16; ++ct) {
        int ch = (ks*4 + g) ^ sw;
        bf16x8 vf = *(const bf16x8*)(Vlds + (ct*16 + lo)*64 + ch*8);
        oacc[ct] = __builtin_amdgcn_mfma_f32_16x16x32_bf16(pa, vf, oacc[ct], 0, 0, 0);
      }
    }
  }

  __syncthreads();
  float linv = 1.f / lrun;
  float l0 = __shfl(linv, 4*g+0), l1 = __shfl(linv, 4*g+1);
  float l2 = __shfl(linv, 4*g+2), l3 = __shfl(linv, 4*g+3);
  float* Ow = Olds + w*4096;
  #pragma unroll
  for (int ct = 0; ct < 16; ++ct) {
    int col = ct*16 + lo;
    Ow[(4*g+0)*256 + col] = oacc[ct][0] * l0;
    Ow[(4*g+1)*256 + col] = oacc[ct][1] * l1;
    Ow[(4*g+2)*256 + col] = oacc[ct][2] * l2;
    Ow[(4*g+3)*256 + col] = oacc[ct][3] * l3;
  }

  f32x4 pacc[16];
  #pragma unroll
  for (int i = 0; i < 16; ++i) pacc[i] = (f32x4){0.f,0.f,0.f,0.f};
  #pragma unroll
  for (int ks = 0; ks < 8; ++ks) {
    const float* ap = Ow + lo*256 + ks*32 + g*8;
    float4 a0 = *(const float4*)ap;
    float4 a1 = *(const float4*)(ap + 4);
    union { u16 h[8]; bf16x8 v; } au;
    au.h[0]=f2bf(a0.x); au.h[1]=f2bf(a0.y); au.h[2]=f2bf(a0.z); au.h[3]=f2bf(a0.w);
    au.h[4]=f2bf(a1.x); au.h[5]=f2bf(a1.y); au.h[6]=f2bf(a1.z); au.h[7]=f2bf(a1.w);
    bf16x8 af = au.v;
    #pragma unroll
    for (int ot = 0; ot < 16; ++ot) {
      const float* wp = w_proj + (size_t)(ot*16 + lo)*NC + ks*32 + g*8;
      float4 b0 = *(const float4*)wp;
      float4 b1 = *(const float4*)(wp + 4);
      union { u16 h[8]; bf16x8 v; } bu;
      bu.h[0]=f2bf(b0.x); bu.h[1]=f2bf(b0.y); bu.h[2]=f2bf(b0.z); bu.h[3]=f2bf(b0.w);
      bu.h[4]=f2bf(b1.x); bu.h[5]=f2bf(b1.y); bu.h[6]=f2bf(b1.z); bu.h[7]=f2bf(b1.w);
      pacc[ot] = __builtin_amdgcn_mfma_f32_16x16x32_bf16(af, bu.v, pacc[ot], 0, 0, 0);
    }
  }

  int nr = n0 + w*16 + 4*g;
  #pragma unroll
  for (int ot = 0; ot < 16; ++ot) {
    int o = ot*16 + lo;
    float bp = b_proj[o];
    size_t base = ((size_t)(b*NC + o)) * NHW + nr;
    float4 xr = *(const float4*)(x + base);
    float4 ov = { pacc[ot][0] + bp + xr.x, pacc[ot][1] + bp + xr.y,
                  pacc[ot][2] + bp + xr.z, pacc[ot][3] + bp + xr.w };
    *(float4*)(out + base) = ov;
  }
}

extern "C" void kernel_launch(void* const* d_in, const int* in_sizes, int n_in,
                              void* d_out, int out_size, void* d_ws, size_t ws_size,
                              hipStream_t stream) {
  const float* x      = (const float*)d_in[0];
  const float* gamma  = (const float*)d_in[1];
  const float* beta   = (const float*)d_in[2];
  const float* w_qkv  = (const float*)d_in[3];
  const float* b_qkv  = (const float*)d_in[4];
  const float* w_proj = (const float*)d_in[5];
  const float* b_proj = (const float*)d_in[6];
  float* out = (float*)d_out;

  char* p = (char*)d_ws;
  float* stats = (float*)p;                           // 512 f
  float* coef  = stats + 2 * NB * NG;                 // 4096 f
  u16* qT = (u16*)(p + 18432);                        // [b][n][c] 16MB
  u16* kF = qT + (size_t)NB * NHW * NC;               // K fragment-linear 16MB
  u16* vF = kF + (size_t)NB * NHW * NC;               // V fragment-linear 16MB
  u16* wqbf = vF + (size_t)NB * NC * NHW;             // qkv W bf16 swizzled, 384KB
  u16* wprojF = wqbf + 3 * NC * NC;                   // proj W fragment-linear, 128KB
  size_t base_end = 18432 + (size_t)3 * NB * NHW * NC * 2
                  + (size_t)3 * NC * NC * 2 + (size_t)NC * NC * 2;
  u16* Praw = (u16*)(p + base_end);                   // [2][b][n][o] bf16, 33.5MB
  float* lsum = (float*)(p + base_end + (size_t)2*NB*NC*NHW*2);   // [2][b][n]
  float* sbuf = lsum + (size_t)2*NB*NHW;
  size_t need_split = base_end + (size_t)2*NB*NC*NHW*2 + (size_t)3*NB*NHW*4;

  gn_stats_k<<<NB * NG, 256, 0, stream>>>(x, stats);
  gn_coef_k<<<(NB * NC + 255) / 256, 256, 0, stream>>>(stats, gamma, beta, coef);
  if (ws_size >= need_split) {
    cvtw2_k<<<NC * NC / 256, 256, 0, stream>>>(w_proj, wprojF);
    cvtw_k<<<3 * NC * NC / 256, 256, 0, stream>>>(w_qkv, wqbf);
    qkv_mfma_k<<<512, 256, 0, stream>>>(x, coef, wqbf, b_qkv, qT, kF, vF);
    attn_split_k<<<512, 256, 0, stream>>>(qT, kF, vF, wprojF, Praw, lsum);
    s_k<<<NB * NHW / 256, 256, 0, stream>>>(lsum, sbuf);
    combine_k<<<1024, 256, 0, stream>>>(x, Praw, Praw + (size_t)NB*NC*NHW,
                                        sbuf, b_proj, out);
  } else {
    qkv_scalar_k<<<NB * 16 * 48, 256, 0, stream>>>(x, coef, w_qkv, b_qkv, qT, kF, vF);
    attn_fb_k<<<512, 256, 0, stream>>>(x, qT, kF, vF, w_proj, b_proj, out);
  }
}

// Round 12
// 216.685 us; speedup vs baseline: 1.2051x; 1.0206x over previous
//
#include <hip/hip_runtime.h>
#include <stdint.h>

#define NB 8
#define NC 256
#define NHW 4096
#define NG 32
#define GELEMS (8*NHW)
#define EPS 1e-5f

typedef unsigned short u16;
typedef unsigned int u32;
typedef __attribute__((ext_vector_type(8))) short bf16x8;
typedef __attribute__((ext_vector_type(4))) float f32x4;
typedef __attribute__((ext_vector_type(16))) float f32x16;

__device__ __forceinline__ float bf2f(u16 u){ return __uint_as_float((u32)u << 16); }
__device__ __forceinline__ u16 f2bf(float f){
  u32 i = __float_as_uint(f);
  u32 r = i + 0x7fffu + ((i >> 16) & 1u);   // RNE
  return (u16)(r >> 16);
}
__device__ __forceinline__ u32 pack2(float a, float b){
  return (u32)f2bf(a) | ((u32)f2bf(b) << 16);
}
__device__ __forceinline__ u32 cvtpk(float lo, float hi){
  u32 r;
  asm("v_cvt_pk_bf16_f32 %0, %1, %2" : "=v"(r) : "v"(lo), "v"(hi));
  return r;
}
__device__ __forceinline__ void plswap(u32 &a, u32 &b){
  asm volatile("v_permlane32_swap_b32 %0, %1" : "+v"(a), "+v"(b));
}

#define GLD16(g, l) __builtin_amdgcn_global_load_lds( \
    (const __attribute__((address_space(1))) u32*)(g), \
    (__attribute__((address_space(3))) u32*)(l), 16, 0, 0)

// ---------------- GroupNorm statistics + fused coef (gn_coef folded in) ----------------
__global__ __launch_bounds__(256) void gn_stats_k(const float* __restrict__ x,
                                                  const float* __restrict__ gamma,
                                                  const float* __restrict__ beta,
                                                  float* __restrict__ coef){
  int bg = blockIdx.x;                       // b*NG + g
  const float* xp = x + (size_t)bg * GELEMS;
  float s = 0.f, s2 = 0.f;
  for (int i = threadIdx.x * 4; i < GELEMS; i += 256 * 4) {
    float4 v = *(const float4*)(xp + i);
    s  += v.x + v.y + v.z + v.w;
    s2 += v.x*v.x + v.y*v.y + v.z*v.z + v.w*v.w;
  }
  #pragma unroll
  for (int off = 32; off; off >>= 1) { s += __shfl_xor(s, off); s2 += __shfl_xor(s2, off); }
  __shared__ float rs[4], rs2[4], sm[2];
  int w = threadIdx.x >> 6;
  if ((threadIdx.x & 63) == 0) { rs[w] = s; rs2[w] = s2; }
  __syncthreads();
  if (threadIdx.x == 0) {
    float ts = rs[0]+rs[1]+rs[2]+rs[3], t2 = rs2[0]+rs2[1]+rs2[2]+rs2[3];
    float mean = ts * (1.f/GELEMS);
    float var  = t2 * (1.f/GELEMS) - mean*mean;
    sm[0] = mean;
    sm[1] = rsqrtf(var + EPS);
  }
  __syncthreads();
  if (threadIdx.x < 8) {
    int b = bg >> 5, g = bg & 31;
    int c = g*8 + threadIdx.x;
    float sc = gamma[c] * sm[1];
    coef[2*(b*NC + c)]     = sc;
    coef[2*(b*NC + c) + 1] = beta[c] - sm[0] * sc;
  }
}

// ---------------- merged weight conversion: wqbf (plain) + wprojF (fragment-linear) ----------------
__global__ __launch_bounds__(256) void cvtall_k(const float* __restrict__ wq,
                                                const float* __restrict__ wp,
                                                u16* __restrict__ wqbf,
                                                u16* __restrict__ wprojF){
  int i = blockIdx.x * 256 + threadIdx.x;     // 4*NC*NC total
  if (i < 3*NC*NC) {
    wqbf[i] = f2bf(wq[i]);
  } else {
    int j = i - 3*NC*NC;
    int e = j & 7, chunk = j >> 3;
    int l = chunk & 63, ks = (chunk >> 6) & 15, ot = chunk >> 10;
    int c = ks*16 + (l>>5)*8 + e;
    int o = ot*32 + (l&31);
    wprojF[j] = f2bf(wp[o*NC + c]);
  }
}

// -------- MFMA fused GN + QKV --------
// Q -> [n][c] bf16 (pre-scaled 1/16).
// K -> fragment-linear: elem(m,c) at ((t*16+kcc)*64 + l)*8 + e,
//      t=m>>5, kcc=c>>4, l=(m&31)+32*((c>>3)&1), e=c&7.
// V -> fragment-linear: elem(c,m) at ((t*16+cv)*64 + l)*8 + e,
//      t=m>>5, cv=((c>>5)&7)+8*((m&31)>>4), l=(c&31)+32*((m>>3)&1), e=m&7.
__global__ __launch_bounds__(256, 2) void qkv_mfma_k(const float* __restrict__ x,
    const float* __restrict__ coef, const u16* __restrict__ wqbf,
    const float* __restrict__ b_qkv,
    u16* __restrict__ qT, u16* __restrict__ kF, u16* __restrict__ vF){
  __shared__ u16 Wbuf[2][4096];              // [16][256] bf16, chunk^=(row&7)

  int bid = blockIdx.x;
  int wg = ((bid & 7) << 6) | (bid >> 3);    // XCD swizzle: batch b -> XCD b
  int b  = wg >> 6;
  int n0 = (wg & 63) << 6;
  int w = threadIdx.x >> 6, lane = threadIdx.x & 63;
  int lo = lane & 15, g = lane >> 4;
  int n = n0 + w*16 + lo;

  int row1 = w*2 + (lane >> 5);
  int sxor = ((lane & 31) ^ (row1 & 7)) * 8;
  int src1 = row1 * 256 + sxor;
  int src2 = (row1 + 8) * 256 + sxor;

  auto STAGE = [&](int bufi, int ot) {
    const u16* src = wqbf + ot * 4096;
    GLD16(src + src1, &Wbuf[bufi][w * 512]);
    GLD16(src + src2, &Wbuf[bufi][2048 + w * 512]);
  };

  STAGE(0, 0);

  bf16x8 hf[8];
  {
    const float* xb = x + (size_t)b * NC * NHW + n;
    const float* cf = coef + b * 512;
    #pragma unroll
    for (int kc = 0; kc < 8; ++kc) {
      union { u32 u[4]; bf16x8 v; } hu;
      #pragma unroll
      for (int p = 0; p < 4; ++p) {
        int c = kc*32 + g*8 + p*2;
        float2 s0 = *(const float2*)(cf + 2*c);
        float2 s1 = *(const float2*)(cf + 2*c + 2);
        float f0 = xb[(size_t)c * NHW]     * s0.x + s0.y;
        float f1 = xb[(size_t)(c+1) * NHW] * s1.x + s1.y;
        hu.u[p] = pack2(f0, f1);
      }
      hf[kc] = hu.v;
    }
  }

  u16* qrow = qT + ((size_t)(b * NHW + n)) * NC;
  u16* kFb = kF + (size_t)b * NHW * NC;
  u16* vFb = vF + (size_t)b * NHW * NC;

  for (int ot = 0; ot < 48; ++ot) {
    __syncthreads();
    if (ot < 47) STAGE((ot + 1) & 1, ot + 1);
    const u16* Wl = Wbuf[ot & 1];
    int sw = lo & 7;
    f32x4 acc = (f32x4){0.f, 0.f, 0.f, 0.f};

    if (ot < 32) {
      // C[o][j]: o = ot*16+4g+r, j (pixel) = lo
      #pragma unroll
      for (int kc = 0; kc < 8; ++kc) {
        bf16x8 wf = *(const bf16x8*)(Wl + lo*256 + ((kc*4 + g) ^ sw) * 8);
        acc = __builtin_amdgcn_mfma_f32_16x16x32_bf16(wf, hf[kc], acc, 0, 0, 0);
      }
      float4 bq = *(const float4*)(b_qkv + ot*16 + 4*g);
      float v0 = acc[0]+bq.x, v1 = acc[1]+bq.y, v2 = acc[2]+bq.z, v3 = acc[3]+bq.w;
      if (ot < 16) {                          // Q, scaled
        v0 *= 0.0625f; v1 *= 0.0625f; v2 *= 0.0625f; v3 *= 0.0625f;
        uint2 st = { pack2(v0, v1), pack2(v2, v3) };
        *(uint2*)(qrow + ot*16 + 4*g) = st;
      } else {                                // K fragment-linear: c = (ot-16)*16+4g+r, m = n
        uint2 st = { pack2(v0, v1), pack2(v2, v3) };
        int cb = (ot-16)*16 + 4*g;
        int l = (n & 31) + 32*((cb >> 3) & 1);
        size_t addr = (((size_t)(n >> 5)*16 + (ot-16))*64 + l)*8 + (cb & 7);
        *(uint2*)(kFb + addr) = st;
      }
    } else {
      // swapped: C[j][o]: j (pixel m) = 4g+r local, o (channel c) = (ot-32)*16+lo
      #pragma unroll
      for (int kc = 0; kc < 8; ++kc) {
        bf16x8 wf = *(const bf16x8*)(Wl + lo*256 + ((kc*4 + g) ^ sw) * 8);
        acc = __builtin_amdgcn_mfma_f32_16x16x32_bf16(hf[kc], wf, acc, 0, 0, 0);
      }
      int oc = (ot - 32) * 16 + lo;           // channel c
      float bv = b_qkv[512 + oc];
      uint2 st = { pack2(acc[0]+bv, acc[1]+bv), pack2(acc[2]+bv, acc[3]+bv) };
      int m = n0 + w*16 + 4*g;                // pixel base (4 consecutive m in elems)
      int cv = ((oc >> 5) & 7) + 8*(w & 1);
      int l = (oc & 31) + 32*((w*2 + (g >> 1)) & 1);
      size_t addr = (((size_t)(m >> 5)*16 + cv)*64 + l)*8 + ((4*g) & 7);
      *(uint2*)(vFb + addr) = st;
    }
  }
}

// ---------------- scalar qkv fallback (old layouts) ----------------
__global__ __launch_bounds__(256) void qkv_scalar_k(const float* __restrict__ x,
                                             const float* __restrict__ coef,
                                             const float* __restrict__ w_qkv,
                                             const float* __restrict__ b_qkv,
                                             u16* __restrict__ qT, u16* __restrict__ kT,
                                             u16* __restrict__ vS){
  int idx0 = blockIdx.x;
  int idx = (idx0 >> 3) + (idx0 & 7) * 768;
  int og = idx % 48;
  int t  = idx / 48;
  int nc = t & 15;
  int b  = t >> 4;
  int n  = nc * 256 + threadIdx.x;
  const float* xb = x + (size_t)b * NC * NHW + n;
  const float* cf = coef + b * NC * 2;
  int ob = og * 16;
  float acc[16];
  #pragma unroll
  for (int j = 0; j < 16; ++j) acc[j] = b_qkv[ob + j];
  for (int c = 0; c < NC; ++c) {
    float h = xb[(size_t)c * NHW] * cf[2*c] + cf[2*c+1];
    const float* wr = w_qkv + (size_t)ob * NC + c;
    #pragma unroll
    for (int j = 0; j < 16; ++j) acc[j] += h * wr[(size_t)j * NC];
  }
  if (ob < 512) {
    float sc = (ob < 256) ? 0.0625f : 1.0f;
    union { u16 h[16]; uint4 q[2]; } u;
    #pragma unroll
    for (int j = 0; j < 16; ++j) u.h[j] = f2bf(acc[j] * sc);
    u16* p = (ob < 256) ? (qT + ((size_t)(b*NHW + n))*NC + ob)
                        : (kT + ((size_t)(b*NHW + n))*NC + (ob - 256));
    *(uint4*)p = u.q[0];
    *(uint4*)(p + 8) = u.q[1];
  } else {
    u16* p = vS + ((size_t)(b*NC) + (ob - 512)) * NHW + n;
    #pragma unroll
    for (int j = 0; j < 16; ++j) p[(size_t)j * NHW] = f2bf(acc[j]);
  }
}

// ========== split-KV flash attention, 32x32 MFMA, fragment-linear K/V ==========
// 512 blocks = (b=8) x (rowblk=32) x (half=2); 4 waves x 32 rows; 2 blocks/CU.
// Staging = pure linear 16KB copy (coalesced); LDS reads contiguous 1KB (0 conflicts).
// No-max softmax; P in-register (cvt_pk + permlane32_swap); bf16 Praw.
// QK chain split into 2 independent half-accumulators (2x MFMA ILP). No setprio.
__global__ __launch_bounds__(256, 2) void attn_split_k(
    const u16* __restrict__ qT, const u16* __restrict__ kF, const u16* __restrict__ vF,
    const u16* __restrict__ wprojF, u16* __restrict__ Praw, float* __restrict__ lsum){
  __shared__ char smem[65536];
  // Kbuf[2] 16KB at 0; Vbuf[2] 16KB at 32768. Epilogue alias: per-wave O 16KB at w*16384.

  int bid = blockIdx.x;
  int b = bid & 7;                           // batch -> XCD
  int u = bid >> 3;
  int rb = u >> 1, h2 = u & 1;
  int n0 = rb << 7;
  int w = threadIdx.x >> 6, lane = threadIdx.x & 63;
  int ln = lane & 31, hl = lane >> 5;

  const u16* qTb = qT + (size_t)b * NHW * NC;
  const u16* kFb = kF + (size_t)b * NHW * NC;
  const u16* vFb = vF + (size_t)b * NHW * NC;

  int nrow = n0 + w*32 + ln;
  bf16x8 qf[16];
  {
    const u16* qp = qTb + (size_t)nrow * NC + hl*8;
    #pragma unroll
    for (int kc = 0; kc < 16; ++kc) qf[kc] = *(const bf16x8*)(qp + kc*16);
  }

  auto STAGE = [&](int bi, int tile){
    const u16* kp = kFb + (size_t)tile * 8192;   // 16KB tile, fragment order
    const u16* vp = vFb + (size_t)tile * 8192;
    char* kb = smem + bi*16384;
    char* vb = smem + 32768 + bi*16384;
    int off = threadIdx.x * 8;                   // elements
    #pragma unroll
    for (int i = 0; i < 4; ++i) {
      GLD16(kp + off + i*2048, kb + threadIdx.x*16 + i*4096);
      GLD16(vp + off + i*2048, vb + threadIdx.x*16 + i*4096);
    }
  };

  f32x16 oacc[8];
  #pragma unroll
  for (int ct = 0; ct < 8; ++ct)
    oacc[ct] = (f32x16){0.f,0.f,0.f,0.f,0.f,0.f,0.f,0.f,0.f,0.f,0.f,0.f,0.f,0.f,0.f,0.f};
  float lrun = 0.f;

  STAGE(0, h2);
  __syncthreads();

  for (int it = 0; it < 64; ++it) {
    int cur = it & 1;
    if (it < 63) STAGE(cur ^ 1, 2*(it+1) + h2);   // interleaved halves: L2 lockstep
    const char* kb = smem + cur*16384;
    const char* vb = smem + 32768 + cur*16384;

    // QK^T (swapped), 2 independent accumulation chains for MFMA ILP
    f32x16 sta = (f32x16){0.f,0.f,0.f,0.f,0.f,0.f,0.f,0.f,0.f,0.f,0.f,0.f,0.f,0.f,0.f,0.f};
    f32x16 stb = sta;
    #pragma unroll
    for (int kc = 0; kc < 8; ++kc) {
      bf16x8 kf0 = *(const bf16x8*)(kb + kc*1024 + lane*16);
      bf16x8 kf1 = *(const bf16x8*)(kb + (kc+8)*1024 + lane*16);
      sta = __builtin_amdgcn_mfma_f32_32x32x16_bf16(kf0, qf[kc],   sta, 0, 0, 0);
      stb = __builtin_amdgcn_mfma_f32_32x32x16_bf16(kf1, qf[kc+8], stb, 0, 0, 0);
    }

    // no-max softmax on sta+stb
    float p[16];
    #pragma unroll
    for (int r = 0; r < 16; ++r) p[r] = __expf(sta[r] + stb[r]);
    lrun += (((p[0]+p[1])+(p[2]+p[3])) + ((p[4]+p[5])+(p[6]+p[7])))
          + (((p[8]+p[9])+(p[10]+p[11])) + ((p[12]+p[13])+(p[14]+p[15])));

    u32 a0 = cvtpk(p[0],  p[1]),  a1 = cvtpk(p[2],  p[3]);
    u32 a2 = cvtpk(p[4],  p[5]),  a3 = cvtpk(p[6],  p[7]);
    u32 a4 = cvtpk(p[8],  p[9]),  a5 = cvtpk(p[10], p[11]);
    u32 a6 = cvtpk(p[12], p[13]), a7 = cvtpk(p[14], p[15]);
    plswap(a0, a2); plswap(a1, a3);          // ks0: m 0..15
    plswap(a4, a6); plswap(a5, a7);          // ks1: m 16..31
    union { u32 u[4]; bf16x8 v; } pa0, pa1;
    pa0.u[0]=a0; pa0.u[1]=a1; pa0.u[2]=a2; pa0.u[3]=a3;
    pa1.u[0]=a4; pa1.u[1]=a5; pa1.u[2]=a6; pa1.u[3]=a7;

    // PV: A=V^T (rows c), B=P^T (cols n) -> O^T  (8 independent chains)
    #pragma unroll
    for (int ks = 0; ks < 2; ++ks) {
      bf16x8 pa = ks ? pa1.v : pa0.v;
      #pragma unroll
      for (int ct = 0; ct < 8; ++ct) {
        bf16x8 vf = *(const bf16x8*)(vb + (ks*8 + ct)*1024 + lane*16);
        oacc[ct] = __builtin_amdgcn_mfma_f32_32x32x16_bf16(vf, pa, oacc[ct], 0, 0, 0);
      }
    }
    __syncthreads();
  }

  lrun += __shfl_xor(lrun, 32);
  if (lane < 32) lsum[((size_t)(h2*NB + b))*NHW + n0 + w*32 + lane] = lrun;

  // ---------------- epilogue: O -> LDS [32 n][256 c] bf16 (XOR swizzle) ----------------
  u16* Ol = (u16*)(smem + w*16384);
  #pragma unroll
  for (int ct = 0; ct < 8; ++ct) {
    u32 c0 = cvtpk(oacc[ct][0],  oacc[ct][1]),  c1 = cvtpk(oacc[ct][2],  oacc[ct][3]);
    u32 c2 = cvtpk(oacc[ct][4],  oacc[ct][5]),  c3 = cvtpk(oacc[ct][6],  oacc[ct][7]);
    u32 c4 = cvtpk(oacc[ct][8],  oacc[ct][9]),  c5 = cvtpk(oacc[ct][10], oacc[ct][11]);
    u32 c6 = cvtpk(oacc[ct][12], oacc[ct][13]), c7 = cvtpk(oacc[ct][14], oacc[ct][15]);
    plswap(c0, c2); plswap(c1, c3);
    plswap(c4, c6); plswap(c5, c7);
    uint4 w0 = {c0, c1, c2, c3};
    uint4 w1 = {c4, c5, c6, c7};
    *(uint4*)(Ol + ln*256 + (((ct*4 + 0 + hl) ^ ln)) * 8) = w0;
    *(uint4*)(Ol + ln*256 + (((ct*4 + 2 + hl) ^ ln)) * 8) = w1;
  }

  // proj: D[n][o] = O[n][c] x W^T[c][o]; W fragment-linear from global (L2-hot)
  f32x16 pacc[8];
  #pragma unroll
  for (int ot = 0; ot < 8; ++ot)
    pacc[ot] = (f32x16){0.f,0.f,0.f,0.f,0.f,0.f,0.f,0.f,0.f,0.f,0.f,0.f,0.f,0.f,0.f,0.f};
  #pragma unroll
  for (int ks = 0; ks < 16; ++ks) {
    bf16x8 af = *(const bf16x8*)(Ol + ln*256 + (((ks*2 + hl) ^ ln)) * 8);
    #pragma unroll
    for (int ot = 0; ot < 8; ++ot) {
      bf16x8 wf = *(const bf16x8*)(wprojF + ((size_t)(ot*16 + ks)*64 + lane) * 8);
      pacc[ot] = __builtin_amdgcn_mfma_f32_32x32x16_bf16(af, wf, pacc[ot], 0, 0, 0);
    }
  }
  // store Praw [n][o] bf16: per r, lanes cover o contiguous (64B) -> coalesced
  u16* Pr = Praw + ((size_t)(h2*NB + b)) * NHW * NC;
  #pragma unroll
  for (int ot = 0; ot < 8; ++ot) {
    int o = ot*32 + ln;
    #pragma unroll
    for (int r = 0; r < 16; ++r) {
      int n = n0 + w*32 + (r & 3) + 8*(r >> 2) + 4*hl;
      Pr[(size_t)n * NC + o] = f2bf(pacc[ot][r]);
    }
  }
}

// ---------------- combine (s_k fused): out = x + bias + (P0+P1)/(l0+l1) ----------------
// 1024 blocks = 8b x 128 n-tiles of 32. P bf16; LDS transpose [32 n][256 o] f32 (pad 258).
__global__ __launch_bounds__(256) void combine_k(const float* __restrict__ x,
    const u16* __restrict__ P0, const u16* __restrict__ P1,
    const float* __restrict__ lsum, const float* __restrict__ b_proj,
    float* __restrict__ out){
  __shared__ float T[32 * 258];
  int bid = blockIdx.x;
  int b = bid & 7, nt = bid >> 3;
  int n0c = nt * 32;
  const u16* p0 = P0 + ((size_t)b * NHW + n0c) * NC;
  const u16* p1 = P1 + ((size_t)b * NHW + n0c) * NC;
  int t = threadIdx.x;
  int nl = t >> 3;
  #pragma unroll
  for (int j = 0; j < 4; ++j) {
    int cc = (t & 7) * 8 + j * 64;            // 8 consecutive u16 cols per thread
    uint4 a = *(const uint4*)(p0 + nl*NC + cc);
    uint4 c = *(const uint4*)(p1 + nl*NC + cc);
    float* tp = T + nl*258 + cc;
    tp[0] = bf2f((u16)(a.x & 0xffff)) + bf2f((u16)(c.x & 0xffff));
    tp[1] = bf2f((u16)(a.x >> 16))    + bf2f((u16)(c.x >> 16));
    tp[2] = bf2f((u16)(a.y & 0xffff)) + bf2f((u16)(c.y & 0xffff));
    tp[3] = bf2f((u16)(a.y >> 16))    + bf2f((u16)(c.y >> 16));
    tp[4] = bf2f((u16)(a.z & 0xffff)) + bf2f((u16)(c.z & 0xffff));
    tp[5] = bf2f((u16)(a.z >> 16))    + bf2f((u16)(c.z >> 16));
    tp[6] = bf2f((u16)(a.w & 0xffff)) + bf2f((u16)(c.w & 0xffff));
    tp[7] = bf2f((u16)(a.w >> 16))    + bf2f((u16)(c.w >> 16));
  }
  int n = t & 31, og = t >> 5;
  float l0 = lsum[(size_t)b*NHW + n0c + n];
  float l1 = lsum[(size_t)NB*NHW + (size_t)b*NHW + n0c + n];
  float sv = 1.f / (l0 + l1);
  __syncthreads();
  #pragma unroll 4
  for (int pass = 0; pass < 32; ++pass) {
    int o = pass*8 + og;
    size_t base = ((size_t)(b*NC + o))*NHW + n0c + n;
    out[base] = x[base] + b_proj[o] + sv * T[n*258 + o];
  }
}

// ---------------- fallback: R3 fused attention (old layouts) ----------------
__global__ __launch_bounds__(256, 2) void attn_fb_k(const float* __restrict__ x,
    const u16* __restrict__ qT, const u16* __restrict__ kT, const u16* __restrict__ vS,
    const float* __restrict__ w_proj, const float* __restrict__ b_proj,
    float* __restrict__ out){
  __shared__ char smem[73728];
  u16* Klds = (u16*)smem;
  u16* Vlds = (u16*)(smem + 32768);
  float* Olds = (float*)smem;

  int bid = blockIdx.x;
  int wg = ((bid & 7) << 6) | (bid >> 3);
  int b  = wg >> 6;
  int n0 = (wg & 63) << 6;
  int w = threadIdx.x >> 6, lane = threadIdx.x & 63;
  int lo = lane & 15, g = lane >> 4;
  int sw = lo & 7;

  const u16* qTb = qT + (size_t)b * NHW * NC;
  const u16* kTb = kT + (size_t)b * NHW * NC;
  const u16* vSb = vS + (size_t)b * NC * NHW;

  bf16x8 qf[8];
  {
    const u16* qp = qTb + (size_t)(n0 + w*16 + lo) * NC + g*8;
    #pragma unroll
    for (int kc = 0; kc < 8; ++kc) qf[kc] = *(const bf16x8*)(qp + kc*32);
  }

  int koff[8], voff[8];
  #pragma unroll
  for (int i = 0; i < 8; ++i) {
    int o = w*8192 + i*1024 + lane*16;
    int mr = o >> 9;
    int kch = ((o >> 4) & 31) ^ (mr & 7);
    koff[i] = mr*NC + kch*8;
    int cr = o >> 7;
    int vch = ((o >> 4) & 7) ^ (cr & 7);
    voff[i] = cr*NHW + vch*8;
  }

  f32x4 oacc[16];
  #pragma unroll
  for (int i = 0; i < 16; ++i) oacc[i] = (f32x4){0.f,0.f,0.f,0.f};
  float mrun = -1e30f, lrun = 0.f;

  char* Pw = smem + 65536 + w*2048;

  for (int m0 = 0; m0 < NHW; m0 += 64) {
    __syncthreads();
    const u16* kp = kTb + (size_t)m0 * NC;
    const u16* vp = vSb + m0;
    #pragma unroll
    for (int i = 0; i < 8; ++i) {
      GLD16(kp + koff[i], smem + w*8192 + i*1024);
      GLD16(vp + voff[i], smem + 32768 + w*8192 + i*1024);
    }
    __syncthreads();

    f32x4 st[4];
    #pragma unroll
    for (int mt = 0; mt < 4; ++mt) st[mt] = (f32x4){0.f,0.f,0.f,0.f};
    #pragma unroll
    for (int kc = 0; kc < 8; ++kc) {
      #pragma unroll
      for (int mt = 0; mt < 4; ++mt) {
        int ch = (kc*4 + g) ^ sw;
        bf16x8 kf = *(const bf16x8*)(Klds + (mt*16 + lo)*NC + ch*8);
        st[mt] = __builtin_amdgcn_mfma_f32_16x16x32_bf16(kf, qf[kc], st[mt], 0, 0, 0);
      }
    }

    float pmax = -1e30f;
    #pragma unroll
    for (int mt = 0; mt < 4; ++mt)
      #pragma unroll
      for (int r = 0; r < 4; ++r) pmax = fmaxf(pmax, st[mt][r]);
    pmax = fmaxf(pmax, __shfl_xor(pmax, 16));
    pmax = fmaxf(pmax, __shfl_xor(pmax, 32));

    if (!__all(pmax - mrun <= 8.f)) {
      float mnew = fmaxf(mrun, pmax);
      float corr = __expf(mrun - mnew);
      mrun = mnew;
      lrun *= corr;
      float c0 = __shfl(corr, 4*g+0), c1 = __shfl(corr, 4*g+1);
      float c2 = __shfl(corr, 4*g+2), c3 = __shfl(corr, 4*g+3);
      #pragma unroll
      for (int ct = 0; ct < 16; ++ct) {
        oacc[ct][0] *= c0; oacc[ct][1] *= c1; oacc[ct][2] *= c2; oacc[ct][3] *= c3;
      }
    }

    float psum = 0.f;
    #pragma unroll
    for (int mt = 0; mt < 4; ++mt) {
      float p0 = __expf(st[mt][0] - mrun);
      float p1 = __expf(st[mt][1] - mrun);
      float p2 = __expf(st[mt][2] - mrun);
      float p3 = __expf(st[mt][3] - mrun);
      psum += (p0 + p1) + (p2 + p3);
      uint2 pk = { pack2(p0, p1), pack2(p2, p3) };
      *(uint2*)(Pw + lo*128 + ((((2*mt + (g>>1)) ^ sw)) << 4) + ((g&1) << 3)) = pk;
    }
    psum += __shfl_xor(psum, 16);
    psum += __shfl_xor(psum, 32);
    lrun += psum;

    #pragma unroll
    for (int ks = 0; ks < 2; ++ks) {
      bf16x8 pa = *(const bf16x8*)(Pw + lo*128 + (((ks*4 + g) ^ sw) << 4));
      #pragma unroll
      for (int ct = 0; ct < 16; ++ct) {
        int ch = (ks*4 + g) ^ sw;
        bf16x8 vf = *(const bf16x8*)(Vlds + (ct*16 + lo)*64 + ch*8);
        oacc[ct] = __builtin_amdgcn_mfma_f32_16x16x32_bf16(pa, vf, oacc[ct], 0, 0, 0);
      }
    }
  }

  __syncthreads();
  float linv = 1.f / lrun;
  float l0 = __shfl(linv, 4*g+0), l1 = __shfl(linv, 4*g+1);
  float l2 = __shfl(linv, 4*g+2), l3 = __shfl(linv, 4*g+3);
  float* Ow = Olds + w*4096;
  #pragma unroll
  for (int ct = 0; ct < 16; ++ct) {
    int col = ct*16 + lo;
    Ow[(4*g+0)*256 + col] = oacc[ct][0] * l0;
    Ow[(4*g+1)*256 + col] = oacc[ct][1] * l1;
    Ow[(4*g+2)*256 + col] = oacc[ct][2] * l2;
    Ow[(4*g+3)*256 + col] = oacc[ct][3] * l3;
  }

  f32x4 pacc[16];
  #pragma unroll
  for (int i = 0; i < 16; ++i) pacc[i] = (f32x4){0.f,0.f,0.f,0.f};
  #pragma unroll
  for (int ks = 0; ks < 8; ++ks) {
    const float* ap = Ow + lo*256 + ks*32 + g*8;
    float4 a0 = *(const float4*)ap;
    float4 a1 = *(const float4*)(ap + 4);
    union { u16 h[8]; bf16x8 v; } au;
    au.h[0]=f2bf(a0.x); au.h[1]=f2bf(a0.y); au.h[2]=f2bf(a0.z); au.h[3]=f2bf(a0.w);
    au.h[4]=f2bf(a1.x); au.h[5]=f2bf(a1.y); au.h[6]=f2bf(a1.z); au.h[7]=f2bf(a1.w);
    bf16x8 af = au.v;
    #pragma unroll
    for (int ot = 0; ot < 16; ++ot) {
      const float* wp = w_proj + (size_t)(ot*16 + lo)*NC + ks*32 + g*8;
      float4 b0 = *(const float4*)wp;
      float4 b1 = *(const float4*)(wp + 4);
      union { u16 h[8]; bf16x8 v; } bu;
      bu.h[0]=f2bf(b0.x); bu.h[1]=f2bf(b0.y); bu.h[2]=f2bf(b0.z); bu.h[3]=f2bf(b0.w);
      bu.h[4]=f2bf(b1.x); bu.h[5]=f2bf(b1.y); bu.h[6]=f2bf(b1.z); bu.h[7]=f2bf(b1.w);
      pacc[ot] = __builtin_amdgcn_mfma_f32_16x16x32_bf16(af, bu.v, pacc[ot], 0, 0, 0);
    }
  }

  int nr = n0 + w*16 + 4*g;
  #pragma unroll
  for (int ot = 0; ot < 16; ++ot) {
    int o = ot*16 + lo;
    float bp = b_proj[o];
    size_t base = ((size_t)(b*NC + o)) * NHW + nr;
    float4 xr = *(const float4*)(x + base);
    float4 ov = { pacc[ot][0] + bp + xr.x, pacc[ot][1] + bp + xr.y,
                  pacc[ot][2] + bp + xr.z, pacc[ot][3] + bp + xr.w };
    *(float4*)(out + base) = ov;
  }
}

extern "C" void kernel_launch(void* const* d_in, const int* in_sizes, int n_in,
                              void* d_out, int out_size, void* d_ws, size_t ws_size,
                              hipStream_t stream) {
  const float* x      = (const float*)d_in[0];
  const float* gamma  = (const float*)d_in[1];
  const float* beta   = (const float*)d_in[2];
  const float* w_qkv  = (const float*)d_in[3];
  const float* b_qkv  = (const float*)d_in[4];
  const float* w_proj = (const float*)d_in[5];
  const float* b_proj = (const float*)d_in[6];
  float* out = (float*)d_out;

  char* p = (char*)d_ws;
  float* coef  = (float*)p;                           // 4096 f (stats fused in)
  u16* qT = (u16*)(p + 18432);                        // [b][n][c] 16MB
  u16* kF = qT + (size_t)NB * NHW * NC;               // K fragment-linear 16MB
  u16* vF = kF + (size_t)NB * NHW * NC;               // V fragment-linear 16MB
  u16* wqbf = vF + (size_t)NB * NC * NHW;             // qkv W bf16 swizzled, 384KB
  u16* wprojF = wqbf + 3 * NC * NC;                   // proj W fragment-linear, 128KB
  size_t base_end = 18432 + (size_t)3 * NB * NHW * NC * 2
                  + (size_t)3 * NC * NC * 2 + (size_t)NC * NC * 2;
  u16* Praw = (u16*)(p + base_end);                   // [2][b][n][o] bf16, 33.5MB
  float* lsum = (float*)(p + base_end + (size_t)2*NB*NC*NHW*2);   // [2][b][n]
  size_t need_split = base_end + (size_t)2*NB*NC*NHW*2 + (size_t)2*NB*NHW*4;

  gn_stats_k<<<NB * NG, 256, 0, stream>>>(x, gamma, beta, coef);
  if (ws_size >= need_split) {
    cvtall_k<<<4 * NC * NC / 256, 256, 0, stream>>>(w_qkv, w_proj, wqbf, wprojF);
    qkv_mfma_k<<<512, 256, 0, stream>>>(x, coef, wqbf, b_qkv, qT, kF, vF);
    attn_split_k<<<512, 256, 0, stream>>>(qT, kF, vF, wprojF, Praw, lsum);
    combine_k<<<1024, 256, 0, stream>>>(x, Praw, Praw + (size_t)NB*NC*NHW,
                                        lsum, b_proj, out);
  } else {
    qkv_scalar_k<<<NB * 16 * 48, 256, 0, stream>>>(x, coef, w_qkv, b_qkv, qT, kF, vF);
    attn_fb_k<<<512, 256, 0, stream>>>(x, qT, kF, vF, w_proj, b_proj, out);
  }
}